// Round 9
// baseline (466.823 us; speedup 1.0000x reference)
//
#include <hip/hip_runtime.h>
#include <math.h>

// GCN on MI355X. N=200000 nodes, E=6400000 edges.
// R23: R22 exposed the true build profile: k_build 82us with WRITE 225MB --
// 9x amp from random 4B adj stores thrashing per-XCD L2 (2 blk/CU x 256 CU
// x 64KB regions = 4MB = exactly L2). Fix: HALF-BIN blocks (grid 782; half-1
// base = base + (m - mytot), no extra scan) stage adj in LDS astg[8832]
// (+7sigma, direct-store overflow fallback) and flush with coalesced 4B
// stores -> zero write amp. Cost: stg read 2x (+25.6MB streaming) << 195MB
// of eliminated writes. LDS 64.0KB.
// k_scat was 81us at occ 27% (grid 512 = 2 blk/CU; cap is 4): NBL 512->1024
// (SEG 6250) -> 32 waves/CU concurrency; k_scanrow reworked for 1024 rows.
// Gathers (R18 phases, R17 packed rows, UN=4) unchanged.
// MESSAGES STAY FP32 (R7: bf16 fails 0.21).

static constexpr int NN = 200000;
static constexpr int NE = 6400000;
static constexpr int BK = 256;

static constexpr int SUBW  = 512;                    // scat/count bin width (d>>9)
static constexpr int NBA   = (NN + SUBW - 1) / SUBW; // 391 bins
static constexpr int NBB   = 2 * NBA;                // 782 half-bin build blocks
static constexpr int NBL   = 1024;                   // count/scatter blocks
static constexpr int BKC   = 512;                    // threads in count/scatter
static constexpr int SEG   = (NE + NBL - 1) / NBL;   // 6250 edges per block
static constexpr int LCAP  = 8832;                   // half-bin LDS staging cap (+7 sigma)
static constexpr int SRCSH = 13;                     // src-bucket shift (8K nodes)
static constexpr int NSB   = (NN + (1 << SRCSH) - 1) >> SRCSH;  // 25 buckets

static constexpr int S     = 4;                      // lanes per node in gathers
static constexpr int LOGS  = 2;

// ---------- build pass 1: per-block LDS histogram (no return deps) ----------
__global__ void __launch_bounds__(BKC) k_count(const int* __restrict__ dstI,
                                               int* __restrict__ hist, int e) {
  __shared__ int cnt[NBA];
  for (int t = threadIdx.x; t < NBA; t += BKC) cnt[t] = 0;
  __syncthreads();
  int blk = blockIdx.x;
  int st = blk * SEG, en = st + SEG; if (en > e) en = e;
  int i = st + (int)threadIdx.x;
  for (; i + 3 * BKC < en; i += 4 * BKC) {
    int d0 = __builtin_nontemporal_load(dstI + i);
    int d1 = __builtin_nontemporal_load(dstI + i + BKC);
    int d2 = __builtin_nontemporal_load(dstI + i + 2 * BKC);
    int d3 = __builtin_nontemporal_load(dstI + i + 3 * BKC);
    atomicAdd(&cnt[d0 >> 9], 1);
    atomicAdd(&cnt[d1 >> 9], 1);
    atomicAdd(&cnt[d2 >> 9], 1);
    atomicAdd(&cnt[d3 >> 9], 1);
  }
  for (; i < en; i += BKC) {
    int d = __builtin_nontemporal_load(dstI + i);
    atomicAdd(&cnt[d >> 9], 1);
  }
  __syncthreads();
  for (int t = threadIdx.x; t < NBA; t += BKC) hist[(size_t)t * NBL + blk] = cnt[t];
}

// ---------- build pass 2a: per-bin exclusive scan over 1024 blocks ----------
__global__ void __launch_bounds__(256) k_scanrow(int* __restrict__ hist,
                                                 int* __restrict__ tot) {
  __shared__ int s0[256], s1[256];
  int b = blockIdx.x, t = threadIdx.x;
  int* row = hist + (size_t)b * NBL;
  uint4 vv = ((const uint4*)row)[t];           // row 16B-aligned (NBL%4==0)
  int v0 = (int)vv.x, v1 = (int)vv.y, v2 = (int)vv.z, v3 = (int)vv.w;
  int s = v0 + v1 + v2 + v3;
  s0[t] = s;
  __syncthreads();
  int* a = s0; int* bb = s1;
  for (int o = 1; o < 256; o <<= 1) {
    bb[t] = a[t] + ((t >= o) ? a[t - o] : 0);
    __syncthreads();
    int* tmp = a; a = bb; bb = tmp;
  }
  int ex = a[t] - s;                 // exclusive over quads
  uint4 w;
  w.x = (unsigned)ex;
  w.y = (unsigned)(ex + v0);
  w.z = (unsigned)(ex + v0 + v1);
  w.w = (unsigned)(ex + v0 + v1 + v2);
  ((uint4*)row)[t] = w;
  if (t == 255) tot[b] = a[t];
}

// ---------- build pass 2b: exclusive scan of bin totals -> dense bases ----------
__global__ void k_scanbin(const int* __restrict__ tot, int* __restrict__ sbase) {
  __shared__ int s0[512], s1[512];
  int t = threadIdx.x;
  int v = (t < NBA) ? tot[t] : 0;
  s0[t] = v;
  __syncthreads();
  int* a = s0; int* b = s1;
  for (int o = 1; o < 512; o <<= 1) {
    b[t] = a[t] + ((t >= o) ? a[t - o] : 0);
    __syncthreads();
    int* tmp = a; a = b; b = tmp;
  }
  if (t < NBA) sbase[t] = a[t] - v;
  if (t == NBA - 1) sbase[NBA] = a[t];   // == E
}

// ---------- build pass 3: block-private-cursor scatter into dense stg ----------
__global__ void __launch_bounds__(BKC) k_scat(const int* __restrict__ srcI,
                                              const int* __restrict__ dstI,
                                              const int* __restrict__ hist,
                                              const int* __restrict__ sbase,
                                              unsigned* __restrict__ stg, int e) {
  __shared__ int cur[NBA];
  int blk = blockIdx.x;
  for (int t = threadIdx.x; t < NBA; t += BKC)
    cur[t] = sbase[t] + hist[(size_t)t * NBL + blk];   // block-private subrange
  __syncthreads();
  int st = blk * SEG, en = st + SEG; if (en > e) en = e;
  int i = st + (int)threadIdx.x;
  for (; i + 3 * BKC < en; i += 4 * BKC) {
    int s0v = __builtin_nontemporal_load(srcI + i);
    int d0 = __builtin_nontemporal_load(dstI + i);
    int s1v = __builtin_nontemporal_load(srcI + i + BKC);
    int d1 = __builtin_nontemporal_load(dstI + i + BKC);
    int s2v = __builtin_nontemporal_load(srcI + i + 2 * BKC);
    int d2 = __builtin_nontemporal_load(dstI + i + 2 * BKC);
    int s3v = __builtin_nontemporal_load(srcI + i + 3 * BKC);
    int d3 = __builtin_nontemporal_load(dstI + i + 3 * BKC);
    int p0 = atomicAdd(&cur[d0 >> 9], 1);
    int p1 = atomicAdd(&cur[d1 >> 9], 1);
    int p2 = atomicAdd(&cur[d2 >> 9], 1);
    int p3 = atomicAdd(&cur[d3 >> 9], 1);
    stg[p0] = ((unsigned)(d0 & (SUBW - 1)) << 18) | (unsigned)s0v;
    stg[p1] = ((unsigned)(d1 & (SUBW - 1)) << 18) | (unsigned)s1v;
    stg[p2] = ((unsigned)(d2 & (SUBW - 1)) << 18) | (unsigned)s2v;
    stg[p3] = ((unsigned)(d3 & (SUBW - 1)) << 18) | (unsigned)s3v;
  }
  for (; i < en; i += BKC) {
    int sv = __builtin_nontemporal_load(srcI + i);
    int d = __builtin_nontemporal_load(dstI + i);
    int p = atomicAdd(&cur[d >> 9], 1);
    stg[p] = ((unsigned)(d & (SUBW - 1)) << 18) | (unsigned)sv;
  }
}

// ---------- pass 4: half-bin ordered build with LDS-staged adj flush ----------
// Block b2 handles half (b2&1) of bin (b2>>1): 256 dst nodes. Reads the full
// bin's stg (2x read), histograms/scatters only its half into astg, flushes
// coalesced. half1 base offset = base + (m - mytot) -- no extra scan needed.
__global__ void __launch_bounds__(BK) k_build(const unsigned* __restrict__ stg,
                                              const int* __restrict__ sbase,
                                              int* __restrict__ rowptr,
                                              int* __restrict__ adj,
                                              int* __restrict__ b8,
                                              int* __restrict__ b13,
                                              int* __restrict__ b17) {
  __shared__ unsigned hist2[256 * NSB];    // 25.6 KB: [dl_half][sb]
  __shared__ int htot[256];
  __shared__ int s0[256], s1[256];
  __shared__ unsigned astg[LCAP];          // 35.3 KB staged adj (total 64.0KB)
  int b2 = blockIdx.x;
  int bin = b2 >> 1, half = b2 & 1;
  int base = sbase[bin];
  int m = sbase[bin + 1] - base;
  size_t off = (size_t)base;
  if (b2 == 0 && threadIdx.x == 0) rowptr[NN] = sbase[NBA];   // == E
  for (int t = threadIdx.x; t < 256 * NSB; t += BK) hist2[t] = 0;
  __syncthreads();
  // read 1: histogram of this half
  for (int k = threadIdx.x; k < m; k += BK) {
    unsigned rec = stg[off + k];
    int dl = (int)(rec >> 18);
    if ((dl >> 8) == half) {
      int sb = (int)((rec & 0x3FFFFu) >> SRCSH);
      atomicAdd(&hist2[(dl & 255) * NSB + sb], 1u);
    }
  }
  __syncthreads();
  // per-dl exclusive scan over sb (one dl per thread; BK==256)
  {
    int dl = threadIdx.x;
    unsigned run = 0;
    for (int sb = 0; sb < NSB; ++sb) {
      unsigned c = hist2[dl * NSB + sb];
      hist2[dl * NSB + sb] = run;
      run += c;
    }
    htot[dl] = (int)run;
    s0[dl] = (int)run;
  }
  __syncthreads();
  // block inclusive scan over 256 dls (ping-pong)
  int* a = s0; int* bb = s1;
  for (int o2 = 1; o2 < 256; o2 <<= 1) {
    int t = threadIdx.x;
    bb[t] = a[t] + ((t >= o2) ? a[t - o2] : 0);
    __syncthreads();
    int* tmp = a; a = bb; bb = tmp;
  }
  int mytot = a[255];
  int base_eff = base + (half ? (m - mytot) : 0);
  {
    int t = threadIdx.x;
    int node = bin * SUBW + half * 256 + t;
    int ex = a[t] - htot[t];
    if (node < NN) {
      rowptr[node] = base_eff + ex;
      b8[node]  = base_eff + ex + (int)hist2[t * NSB + 8];   // exclusive prefix
      b13[node] = base_eff + ex + (int)hist2[t * NSB + 13];
      b17[node] = base_eff + ex + (int)hist2[t * NSB + 17];
    }
    bb[t] = ex;
  }
  __syncthreads();
  // read 2: ordered scatter into LDS staging (overflow -> direct store)
  for (int k = threadIdx.x; k < m; k += BK) {
    unsigned rec = stg[off + k];
    int dl = (int)(rec >> 18);
    if ((dl >> 8) != half) continue;
    unsigned src = rec & 0x3FFFFu;
    int sb = (int)(src >> SRCSH);
    int p = bb[dl & 255] + (int)atomicAdd(&hist2[(dl & 255) * NSB + sb], 1u);
    if (p < LCAP) astg[p] = src;
    else adj[base_eff + p] = (int)src;
  }
  __syncthreads();
  // coalesced flush: zero write amplification
  int mm = mytot < LCAP ? mytot : LCAP;
  for (int k = threadIdx.x; k < mm; k += BK) adj[base_eff + k] = (int)astg[k];
}

// dinv + p1 = dinv*x in one pass (12B rows)
__global__ void k_prep(const float* __restrict__ x, const int* __restrict__ rowptr,
                       float* __restrict__ dinv, float* __restrict__ p1, int n) {
  int i = blockIdx.x * blockDim.x + threadIdx.x;
  if (i >= n) return;
  float di = rsqrtf(1.0f + (float)(rowptr[i + 1] - rowptr[i]));
  dinv[i] = di;
  float3 v;
  v.x = di * x[3 * (size_t)i];
  v.y = di * x[3 * (size_t)i + 1];
  v.z = di * x[3 * (size_t)i + 2];
  *(float3*)(p1 + 3 * (size_t)i) = v;
}

// ---------- packed-row load/accumulate/store (RW floats per row) ----------
template <int RW> struct RowT;
template <> struct RowT<3> {
  using T = float3;   // 12B rows
  static __device__ inline T ld(const float* __restrict__ p) { return *(const float3*)p; }
  static __device__ inline void add(float* __restrict__ a, const T& v) {
    a[0] += v.x; a[1] += v.y; a[2] += v.z;
  }
  static __device__ inline void st(float* __restrict__ p, const float* __restrict__ a) {
    *(float3*)p = make_float3(a[0], a[1], a[2]);
  }
};
template <> struct RowT<6> {
  struct T { float2 a, b, c; };       // 24B rows, 8B-aligned
  static __device__ inline T ld(const float* __restrict__ p) {
    T t; t.a = *(const float2*)p; t.b = *(const float2*)(p + 2); t.c = *(const float2*)(p + 4);
    return t;
  }
  static __device__ inline void add(float* __restrict__ a, const T& v) {
    a[0] += v.a.x; a[1] += v.a.y; a[2] += v.b.x; a[3] += v.b.y; a[4] += v.c.x; a[5] += v.c.y;
  }
  static __device__ inline void st(float* __restrict__ p, const float* __restrict__ a) {
    *(float2*)(p)     = make_float2(a[0], a[1]);
    *(float2*)(p + 2) = make_float2(a[2], a[3]);
    *(float2*)(p + 4) = make_float2(a[4], a[5]);
  }
};
template <> struct RowT<12> {
  struct T { float4 a, b, c; };       // 48B rows, 16B-aligned bases
  static __device__ inline T ld(const float* __restrict__ p) {
    T t; t.a = *(const float4*)p; t.b = *(const float4*)(p + 4); t.c = *(const float4*)(p + 8);
    return t;
  }
  static __device__ inline void add(float* __restrict__ a, const T& v) {
    a[0] += v.a.x; a[1] += v.a.y; a[2] += v.a.z; a[3] += v.a.w;
    a[4] += v.b.x; a[5] += v.b.y; a[6] += v.b.z; a[7] += v.b.w;
    a[8] += v.c.x; a[9] += v.c.y; a[10] += v.c.z; a[11] += v.c.w;
  }
  static __device__ inline void st(float* __restrict__ p, const float* __restrict__ a) {
    *(float4*)(p)     = make_float4(a[0], a[1], a[2], a[3]);
    *(float4*)(p + 4) = make_float4(a[4], a[5], a[6], a[7]);
    *(float4*)(p + 8) = make_float4(a[8], a[9], a[10], a[11]);
  }
};

// ---------- slot-strided gather over [st,en), unroll UN, adj prefetch 1 ahead ----------
template <int RW, int UN>
__device__ inline void gather_p(const int* __restrict__ adj, int st, int en,
                                const float* __restrict__ pin, float* __restrict__ acc,
                                int slot) {
  using RT = RowT<RW>;
  using T = typename RT::T;
  int k = st + slot;
  if (k + (UN - 1) * S < en) {
    int a[UN];
#pragma unroll
    for (int u = 0; u < UN; ++u) a[u] = adj[k + u * S];
    for (;;) {
      int kn = k + UN * S;
      bool more = (kn + (UN - 1) * S < en);
      int b[UN];
#pragma unroll
      for (int u = 0; u < UN; ++u) b[u] = 0;
      if (more) {
#pragma unroll
        for (int u = 0; u < UN; ++u) b[u] = adj[kn + u * S];
      }
      T v[UN];
#pragma unroll
      for (int u = 0; u < UN; ++u) v[u] = RT::ld(pin + (size_t)a[u] * RW);
#pragma unroll
      for (int u = 0; u < UN; ++u) RT::add(acc, v[u]);
      k = kn;
      if (!more) break;
#pragma unroll
      for (int u = 0; u < UN; ++u) a[u] = b[u];
    }
  }
  for (; k < en; k += S) {
    T v = RT::ld(pin + (size_t)adj[k] * RW);
    RT::add(acc, v);
  }
}

// 4-lane butterfly: all lanes end with the full sum
template <int FIN>
__device__ inline void group_reduce(float* __restrict__ acc) {
#pragma unroll
  for (int j = 0; j < FIN; ++j) {
    acc[j] += __shfl_xor(acc[j], 1);
    acc[j] += __shfl_xor(acc[j], 2);
  }
}

// ---------- single-phase fused gather (layer 1 only; slab fits L2) ----------
template <int RW, int FOUT, int MODE>
__global__ void __launch_bounds__(BK, 8) k_gather_fused(
    const int* __restrict__ adj, const int* __restrict__ rowptr,
    const float* __restrict__ pin, const float* __restrict__ W,
    const float* __restrict__ bias, const float* __restrict__ dinv,
    float* __restrict__ pout, int n) {
  __shared__ float sW[RW * FOUT];
  __shared__ float sb[FOUT];
  for (int t = threadIdx.x; t < RW * FOUT; t += BK) sW[t] = W[t];
  if (threadIdx.x < FOUT) sb[threadIdx.x] = bias[threadIdx.x];
  __syncthreads();
  int g = blockIdx.x * blockDim.x + threadIdx.x;
  int i = g >> LOGS;
  int slot = g & (S - 1);
  if (i >= n) return;
  float acc[RW] = {};
  if (slot == 0) {                                  // self-loop on slot 0
    typename RowT<RW>::T v = RowT<RW>::ld(pin + (size_t)i * RW);
    RowT<RW>::add(acc, v);
  }
  gather_p<RW, 4>(adj, rowptr[i], rowptr[i + 1], pin, acc, slot);
  group_reduce<RW>(acc);
  float di = dinv[i];
  float h[FOUT];
  float ss = 0.f;
#pragma unroll
  for (int j = 0; j < FOUT; ++j) {
    float s = 0.f;
#pragma unroll
    for (int kk = 0; kk < RW; ++kk) s = fmaf(acc[kk], sW[kk * FOUT + j], s);
    float t = fmaf(di, s, sb[j]);
    h[j] = t;
    ss += t * t;
  }
  float o[FOUT];
  if (MODE == 0) {
#pragma unroll
    for (int j = 0; j < FOUT; ++j) o[j] = di * tanhf(h[j]);
  } else {
    float inv = 1.f / fmaxf(sqrtf(ss), 1e-12f);
#pragma unroll
    for (int j = 0; j < FOUT; ++j) o[j] = di * tanhf(h[j] * inv);
  }
  if (slot == 0) {
    float* po = pout + (size_t)i * FOUT;
    if (MODE == 0) {                                 // 24B rows: 3x float2
      *(float2*)(po)     = make_float2(o[0], o[1]);
      *(float2*)(po + 2) = make_float2(o[2], o[3]);
      *(float2*)(po + 4) = make_float2(o[4], o[5]);
    } else {                                         // 48B rows: 3x float4
      *(float4*)(po)     = make_float4(o[0], o[1], o[2], o[3]);
      *(float4*)(po + 4) = make_float4(o[4], o[5], o[6], o[7]);
      *(float4*)(po + 8) = make_float4(o[8], o[9], o[10], o[11]);
    }
  }
}

// ---------- phased gather: one src-range slab per kernel launch ----------
// FIRST: acc = self-loop; else acc = reload packed partial (slot 0 holds it).
template <int RW, bool FIRST>
__global__ void __launch_bounds__(BK, 8) k_gphase(
    const int* __restrict__ adj, const int* __restrict__ stA,
    const int* __restrict__ enB, const float* __restrict__ pin,
    float* __restrict__ accb, int n) {
  int g = blockIdx.x * blockDim.x + threadIdx.x;
  int i = g >> LOGS;
  int slot = g & (S - 1);
  if (i >= n) return;
  float acc[RW] = {};
  if (slot == 0) {
    if (FIRST) {
      typename RowT<RW>::T v = RowT<RW>::ld(pin + (size_t)i * RW);  // self-loop
      RowT<RW>::add(acc, v);
    } else {
      typename RowT<RW>::T v = RowT<RW>::ld(accb + (size_t)i * RW); // partial
      RowT<RW>::add(acc, v);
    }
  }
  gather_p<RW, 4>(adj, stA[i], enB[i], pin, acc, slot);
  group_reduce<RW>(acc);
  if (slot == 0) RowT<RW>::st(accb + (size_t)i * RW, acc);
}

// ---------- final phase: last slab + epilogue ----------
// MODE 1: l2norm+tanh -> pout (48B rows for FOUT=12)
// MODE 2: l2norm -> Wc -> l2norm -> out (13 floats)
template <int RW, int FOUT, int MODE>
__global__ void __launch_bounds__(BK, 6) k_gphase_last(
    const int* __restrict__ adj, const int* __restrict__ stA,
    const int* __restrict__ rowptr, const float* __restrict__ pin,
    const float* __restrict__ W, const float* __restrict__ bias,
    const float* __restrict__ Wc, const float* __restrict__ bc,
    const float* __restrict__ dinv, const float* __restrict__ accb,
    float* __restrict__ out, int n) {
  constexpr int FC = 13;
  __shared__ float sW[RW * FOUT];
  __shared__ float sb[FOUT];
  __shared__ float sWc[MODE == 2 ? FOUT * FC : 1];
  __shared__ float sbc[MODE == 2 ? FC : 1];
  for (int t = threadIdx.x; t < RW * FOUT; t += BK) sW[t] = W[t];
  if (threadIdx.x < FOUT) sb[threadIdx.x] = bias[threadIdx.x];
  if (MODE == 2) {
    for (int t = threadIdx.x; t < FOUT * FC; t += BK) sWc[t] = Wc[t];
    if (threadIdx.x < FC) sbc[threadIdx.x] = bc[threadIdx.x];
  }
  __syncthreads();
  int g = blockIdx.x * blockDim.x + threadIdx.x;
  int i = g >> LOGS;
  int slot = g & (S - 1);
  if (i >= n) return;
  float acc[RW] = {};
  if (slot == 0) {
    typename RowT<RW>::T v = RowT<RW>::ld(accb + (size_t)i * RW);   // partial
    RowT<RW>::add(acc, v);
  }
  gather_p<RW, 4>(adj, stA[i], rowptr[i + 1], pin, acc, slot);
  group_reduce<RW>(acc);
  float di = dinv[i];
  float h[FOUT];
  float ss = 0.f;
#pragma unroll
  for (int j = 0; j < FOUT; ++j) {
    float s = 0.f;
#pragma unroll
    for (int kk = 0; kk < RW; ++kk) s = fmaf(acc[kk], sW[kk * FOUT + j], s);
    float t = fmaf(di, s, sb[j]);
    h[j] = t;
    ss += t * t;
  }
  float inv = 1.f / fmaxf(sqrtf(ss), 1e-12f);
  if (MODE == 1) {
    float o[FOUT];
#pragma unroll
    for (int j = 0; j < FOUT; ++j) o[j] = di * tanhf(h[j] * inv);
    if (slot == 0) {
      float* po = out + (size_t)i * FOUT;                  // 48B rows (FOUT=12)
      *(float4*)(po)     = make_float4(o[0], o[1], o[2], o[3]);
      *(float4*)(po + 4) = make_float4(o[4], o[5], o[6], o[7]);
      *(float4*)(po + 8) = make_float4(o[8], o[9], o[10], o[11]);
    }
  } else {
    float v[FC];
    float ss2 = 0.f;
#pragma unroll
    for (int j = 0; j < FC; ++j) {
      float s = sbc[j];
#pragma unroll
      for (int kk = 0; kk < FOUT; ++kk) s = fmaf(h[kk] * inv, sWc[kk * FC + j], s);
      v[j] = s;
      ss2 += s * s;
    }
    float inv2 = 1.f / fmaxf(sqrtf(ss2), 1e-12f);
    if (slot == 0) {
#pragma unroll
      for (int j = 0; j < FC; ++j) out[(size_t)i * FC + j] = v[j] * inv2;
    }
  }
}

extern "C" void kernel_launch(void* const* d_in, const int* in_sizes, int n_in,
                              void* d_out, int out_size, void* d_ws, size_t ws_size,
                              hipStream_t stream) {
  const float* x  = (const float*)d_in[0];
  const int*   ei = (const int*)d_in[1];
  const float* W1 = (const float*)d_in[2];
  const float* b1 = (const float*)d_in[3];
  const float* W2 = (const float*)d_in[4];
  const float* b2 = (const float*)d_in[5];
  const float* W3 = (const float*)d_in[6];
  const float* b3 = (const float*)d_in[7];
  const float* Wc = (const float*)d_in[8];
  const float* bc = (const float*)d_in[9];
  float* out = (float*)d_out;

  const int n = NN;
  const int e = NE;
  const int* srcI = ei;       // row 0
  const int* dstI = ei + e;   // row 1

  // Workspace (words):
  //   dinv[N] | rowptr[N+8] | sbase[512] | tot[512] | hist[NBA*NBL] | adj[E]
  //   | b8[N] | b13[N] | b17[N] | pad->64B | R
  // R hosts dense stg[E]=6.4M words during build, then
  //   p1[3N] | p2[6N] | p3[12N] | accb[12N] (=6.6M words) during gathers.
  // hist = 391*1024 = 400384 words (1.6MB). Total ~= 58 MB (<=76 MB proven).
  float* ws = (float*)d_ws;
  float* dinv  = ws;
  int* rowptr  = (int*)(ws + n);            // N+8 (uses N+1, padded)
  int* sbase   = rowptr + n + 8;            // NBA+1 used
  int* tot     = sbase + 512;
  int* hist    = tot + 512;                 // NBA * NBL (16B-aligned)
  int* adj     = hist + NBA * NBL;
  int* b8      = adj + e;
  int* b13     = b8 + n;
  int* b17     = b13 + n;
  size_t roff = (size_t)n + (n + 8) + 512 + 512 + (size_t)NBA * NBL + e + 3 * (size_t)n;
  roff = (roff + 15) & ~(size_t)15;         // round to 16 words = 64B
  float* R     = ws + roff;
  unsigned* stg = (unsigned*)R;             // dense E words during build
  float* p1   = R;                          // 3N
  float* p2   = R + (size_t)3 * n;          // 6N
  float* p3   = R + (size_t)9 * n;          // 12N
  float* accb = R + (size_t)21 * n;         // 12N packed partials (16B-aligned)

  const int gn  = (n + BK - 1) / BK;
  const int gnS = (n * S + BK - 1) / BK;    // 3125 blocks

  // --- CSR build: count -> scan -> block-private scatter -> half-bin build ---
  k_count<<<NBL, BKC, 0, stream>>>(dstI, hist, e);
  k_scanrow<<<NBA, 256, 0, stream>>>(hist, tot);
  k_scanbin<<<1, 512, 0, stream>>>(tot, sbase);
  k_scat<<<NBL, BKC, 0, stream>>>(srcI, dstI, hist, sbase, stg, e);
  k_build<<<NBB, BK, 0, stream>>>(stg, sbase, rowptr, adj, b8, b13, b17);

  // --- dinv + p1 = dinv * x (12B rows) ---
  k_prep<<<gn, BK, 0, stream>>>(x, rowptr, dinv, p1, n);

  // --- Layer 1 (p1 = 2.4 MB, fits per-XCD L2): single fused phase ---
  k_gather_fused<3, 6, 0><<<gnS, BK, 0, stream>>>(adj, rowptr, p1, W1, b1, dinv, p2, n);

  // --- Layer 2 (p2 = 4.8 MB): 2 phases, cut at bucket 13 ---
  k_gphase<6, true><<<gnS, BK, 0, stream>>>(adj, rowptr, b13, p2, accb, n);
  k_gphase_last<6, 12, 1><<<gnS, BK, 0, stream>>>(adj, b13, rowptr, p2, W2, b2,
                                                  Wc, bc, dinv, accb, p3, n);

  // --- Layer 3 + classifier (p3 = 9.6 MB): 3 phases, cuts at buckets 8/17 ---
  k_gphase<12, true><<<gnS, BK, 0, stream>>>(adj, rowptr, b8, p3, accb, n);
  k_gphase<12, false><<<gnS, BK, 0, stream>>>(adj, b8, b17, p3, accb, n);
  k_gphase_last<12, 24, 2><<<gnS, BK, 0, stream>>>(adj, b17, rowptr, p3, W3, b3,
                                                   Wc, bc, dinv, accb, out, n);
}

// Round 10
// 429.746 us; speedup vs baseline: 1.0863x; 1.0863x over previous
//
#include <hip/hip_runtime.h>
#include <math.h>

// GCN on MI355X. N=200000 nodes, E=6400000 edges.
// R24: R23's staged-flush k_build killed write amp (225->28MB, predicted) but
// dur ROSE 82->92us: 64KB LDS -> 2 blk/CU -> occ 16%, latency-bound (HBM 8.8%,
// VALU 9.4%). Fix the occupancy, keep the staging: QUARTER-BINS (128 dsts,
// grid 1568, 512 thr). LDS = hist2 12.8KB + astg 19.5KB ~= 34KB -> 4 blk x
// 8 waves = 32 waves/CU (100%). The 4x filtered stg read is tamed by an
// XCD-SWIZZLED mapping: the 4 quarters of a bin run on the SAME XCD (8 apart
// in dispatch) -> bin's 16KB stg slab L2-hot after quarter 0. Quarter base =
// base + (# earlier-quarter recs), tallied in the hist pass (per-thread count
// + one atomic). R19 lesson pinned: k_scat bins stay at 391 (block subrange
// >= 1 line; finer bins re-amplify writes). count/scans/scat (NBL=1024) and
// all gathers unchanged. MESSAGES STAY FP32 (R7: bf16 fails 0.21).

static constexpr int NN = 200000;
static constexpr int NE = 6400000;
static constexpr int BK = 256;

static constexpr int SUBW  = 512;                    // scat/count bin width (d>>9)
static constexpr int NBA   = (NN + SUBW - 1) / SUBW; // 391 bins
static constexpr int QDS   = 128;                    // dsts per build quarter
static constexpr int BKB   = 512;                    // build threads
static constexpr int NBB   = ((NBA + 7) / 8) * 8 * 4;// 1568 swizzled build blocks
static constexpr int LCAP  = 4864;                   // quarter staging cap (+12 sigma)
static constexpr int NBL   = 1024;                   // count/scatter blocks
static constexpr int BKC   = 512;                    // threads in count/scatter
static constexpr int SEG   = (NE + NBL - 1) / NBL;   // 6250 edges per block
static constexpr int SRCSH = 13;                     // src-bucket shift (8K nodes)
static constexpr int NSB   = (NN + (1 << SRCSH) - 1) >> SRCSH;  // 25 buckets

static constexpr int S     = 4;                      // lanes per node in gathers
static constexpr int LOGS  = 2;

// ---------- build pass 1: per-block LDS histogram (no return deps) ----------
__global__ void __launch_bounds__(BKC) k_count(const int* __restrict__ dstI,
                                               int* __restrict__ hist, int e) {
  __shared__ int cnt[NBA];
  for (int t = threadIdx.x; t < NBA; t += BKC) cnt[t] = 0;
  __syncthreads();
  int blk = blockIdx.x;
  int st = blk * SEG, en = st + SEG; if (en > e) en = e;
  int i = st + (int)threadIdx.x;
  for (; i + 3 * BKC < en; i += 4 * BKC) {
    int d0 = __builtin_nontemporal_load(dstI + i);
    int d1 = __builtin_nontemporal_load(dstI + i + BKC);
    int d2 = __builtin_nontemporal_load(dstI + i + 2 * BKC);
    int d3 = __builtin_nontemporal_load(dstI + i + 3 * BKC);
    atomicAdd(&cnt[d0 >> 9], 1);
    atomicAdd(&cnt[d1 >> 9], 1);
    atomicAdd(&cnt[d2 >> 9], 1);
    atomicAdd(&cnt[d3 >> 9], 1);
  }
  for (; i < en; i += BKC) {
    int d = __builtin_nontemporal_load(dstI + i);
    atomicAdd(&cnt[d >> 9], 1);
  }
  __syncthreads();
  for (int t = threadIdx.x; t < NBA; t += BKC) hist[(size_t)t * NBL + blk] = cnt[t];
}

// ---------- build pass 2a: per-bin exclusive scan over 1024 blocks ----------
__global__ void __launch_bounds__(256) k_scanrow(int* __restrict__ hist,
                                                 int* __restrict__ tot) {
  __shared__ int s0[256], s1[256];
  int b = blockIdx.x, t = threadIdx.x;
  int* row = hist + (size_t)b * NBL;
  uint4 vv = ((const uint4*)row)[t];           // row 16B-aligned (NBL%4==0)
  int v0 = (int)vv.x, v1 = (int)vv.y, v2 = (int)vv.z, v3 = (int)vv.w;
  int s = v0 + v1 + v2 + v3;
  s0[t] = s;
  __syncthreads();
  int* a = s0; int* bb = s1;
  for (int o = 1; o < 256; o <<= 1) {
    bb[t] = a[t] + ((t >= o) ? a[t - o] : 0);
    __syncthreads();
    int* tmp = a; a = bb; bb = tmp;
  }
  int ex = a[t] - s;                 // exclusive over quads
  uint4 w;
  w.x = (unsigned)ex;
  w.y = (unsigned)(ex + v0);
  w.z = (unsigned)(ex + v0 + v1);
  w.w = (unsigned)(ex + v0 + v1 + v2);
  ((uint4*)row)[t] = w;
  if (t == 255) tot[b] = a[t];
}

// ---------- build pass 2b: exclusive scan of bin totals -> dense bases ----------
__global__ void k_scanbin(const int* __restrict__ tot, int* __restrict__ sbase) {
  __shared__ int s0[512], s1[512];
  int t = threadIdx.x;
  int v = (t < NBA) ? tot[t] : 0;
  s0[t] = v;
  __syncthreads();
  int* a = s0; int* b = s1;
  for (int o = 1; o < 512; o <<= 1) {
    b[t] = a[t] + ((t >= o) ? a[t - o] : 0);
    __syncthreads();
    int* tmp = a; a = b; b = tmp;
  }
  if (t < NBA) sbase[t] = a[t] - v;
  if (t == NBA - 1) sbase[NBA] = a[t];   // == E
}

// ---------- build pass 3: block-private-cursor scatter into dense stg ----------
__global__ void __launch_bounds__(BKC) k_scat(const int* __restrict__ srcI,
                                              const int* __restrict__ dstI,
                                              const int* __restrict__ hist,
                                              const int* __restrict__ sbase,
                                              unsigned* __restrict__ stg, int e) {
  __shared__ int cur[NBA];
  int blk = blockIdx.x;
  for (int t = threadIdx.x; t < NBA; t += BKC)
    cur[t] = sbase[t] + hist[(size_t)t * NBL + blk];   // block-private subrange
  __syncthreads();
  int st = blk * SEG, en = st + SEG; if (en > e) en = e;
  int i = st + (int)threadIdx.x;
  for (; i + 3 * BKC < en; i += 4 * BKC) {
    int s0v = __builtin_nontemporal_load(srcI + i);
    int d0 = __builtin_nontemporal_load(dstI + i);
    int s1v = __builtin_nontemporal_load(srcI + i + BKC);
    int d1 = __builtin_nontemporal_load(dstI + i + BKC);
    int s2v = __builtin_nontemporal_load(srcI + i + 2 * BKC);
    int d2 = __builtin_nontemporal_load(dstI + i + 2 * BKC);
    int s3v = __builtin_nontemporal_load(srcI + i + 3 * BKC);
    int d3 = __builtin_nontemporal_load(dstI + i + 3 * BKC);
    int p0 = atomicAdd(&cur[d0 >> 9], 1);
    int p1 = atomicAdd(&cur[d1 >> 9], 1);
    int p2 = atomicAdd(&cur[d2 >> 9], 1);
    int p3 = atomicAdd(&cur[d3 >> 9], 1);
    stg[p0] = ((unsigned)(d0 & (SUBW - 1)) << 18) | (unsigned)s0v;
    stg[p1] = ((unsigned)(d1 & (SUBW - 1)) << 18) | (unsigned)s1v;
    stg[p2] = ((unsigned)(d2 & (SUBW - 1)) << 18) | (unsigned)s2v;
    stg[p3] = ((unsigned)(d3 & (SUBW - 1)) << 18) | (unsigned)s3v;
  }
  for (; i < en; i += BKC) {
    int sv = __builtin_nontemporal_load(srcI + i);
    int d = __builtin_nontemporal_load(dstI + i);
    int p = atomicAdd(&cur[d >> 9], 1);
    stg[p] = ((unsigned)(d & (SUBW - 1)) << 18) | (unsigned)sv;
  }
}

// ---------- pass 4: quarter-bin ordered build, LDS-staged coalesced flush ----------
// XCD-swizzled: quarters of one bin share an XCD (8 apart in dispatch) so the
// bin's ~16KB stg slab is L2-hot for quarters 1-3. Quarter q's base offset =
// bin base + (# earlier-quarter recs), tallied during the hist read.
__global__ void __launch_bounds__(BKB) k_build(const unsigned* __restrict__ stg,
                                               const int* __restrict__ sbase,
                                               int* __restrict__ rowptr,
                                               int* __restrict__ adj,
                                               int* __restrict__ b8,
                                               int* __restrict__ b13,
                                               int* __restrict__ b17) {
  __shared__ unsigned hist2[QDS * NSB];    // 12.8 KB: [dl_q][sb]
  __shared__ int htot[QDS];
  __shared__ int s0[QDS], s1[QDS];
  __shared__ unsigned astg[LCAP];          // 19.5 KB staged adj (total ~34KB)
  __shared__ int beforeCnt;
  int g = blockIdx.x;
  int x = g & 7, j = g >> 3;
  int q = j & 3;
  int bin = (j >> 2) * 8 + x;              // quarters of bin -> same XCD (g%8)
  if (bin >= NBA) return;
  int base = sbase[bin];
  int m = sbase[bin + 1] - base;
  size_t off = (size_t)base;
  if (g == 0 && threadIdx.x == 0) rowptr[NN] = sbase[NBA];   // == E
  for (int t = threadIdx.x; t < QDS * NSB; t += BKB) hist2[t] = 0;
  if (threadIdx.x == 0) beforeCnt = 0;
  __syncthreads();
  // read 1: histogram this quarter; count earlier-quarter recs for base_eff
  int myBefore = 0;
  for (int k = threadIdx.x; k < m; k += BKB) {
    unsigned rec = stg[off + k];
    int dl = (int)(rec >> 18);
    int dq = dl >> 7;
    if (dq == q) {
      int sb = (int)((rec & 0x3FFFFu) >> SRCSH);
      atomicAdd(&hist2[(dl & (QDS - 1)) * NSB + sb], 1u);
    } else if (dq < q) {
      ++myBefore;
    }
  }
  if (myBefore) atomicAdd(&beforeCnt, myBefore);
  __syncthreads();
  // per-dl exclusive scan over sb (threads 0..127; stride 25 spreads banks)
  if (threadIdx.x < QDS) {
    int dl = threadIdx.x;
    unsigned run = 0;
    for (int sb = 0; sb < NSB; ++sb) {
      unsigned c = hist2[dl * NSB + sb];
      hist2[dl * NSB + sb] = run;
      run += c;
    }
    htot[dl] = (int)run;
    s0[dl] = (int)run;
  }
  __syncthreads();
  // block inclusive scan over 128 dls (ping-pong, 7 iters)
  int* a = s0; int* bb = s1;
  for (int o2 = 1; o2 < QDS; o2 <<= 1) {
    if (threadIdx.x < QDS) {
      int t = threadIdx.x;
      bb[t] = a[t] + ((t >= o2) ? a[t - o2] : 0);
    }
    __syncthreads();
    int* tmp = a; a = bb; bb = tmp;
  }
  int mytot = a[QDS - 1];
  int base_eff = base + beforeCnt;
  if (threadIdx.x < QDS) {
    int t = threadIdx.x;
    int node = bin * SUBW + q * QDS + t;
    int ex = a[t] - htot[t];
    if (node < NN) {
      rowptr[node] = base_eff + ex;
      b8[node]  = base_eff + ex + (int)hist2[t * NSB + 8];   // exclusive prefix
      b13[node] = base_eff + ex + (int)hist2[t * NSB + 13];
      b17[node] = base_eff + ex + (int)hist2[t * NSB + 17];
    }
    bb[t] = ex;
  }
  __syncthreads();
  // read 2 (L2-hot): ordered scatter into LDS staging (overflow -> direct)
  for (int k = threadIdx.x; k < m; k += BKB) {
    unsigned rec = stg[off + k];
    int dl = (int)(rec >> 18);
    if ((dl >> 7) != q) continue;
    unsigned src = rec & 0x3FFFFu;
    int sb = (int)(src >> SRCSH);
    int p = bb[dl & (QDS - 1)] + (int)atomicAdd(&hist2[(dl & (QDS - 1)) * NSB + sb], 1u);
    if (p < LCAP) astg[p] = src;
    else adj[base_eff + p] = (int)src;
  }
  __syncthreads();
  // coalesced flush: zero write amplification
  int mm = mytot < LCAP ? mytot : LCAP;
  for (int k = threadIdx.x; k < mm; k += BKB) adj[base_eff + k] = (int)astg[k];
}

// dinv + p1 = dinv*x in one pass (12B rows)
__global__ void k_prep(const float* __restrict__ x, const int* __restrict__ rowptr,
                       float* __restrict__ dinv, float* __restrict__ p1, int n) {
  int i = blockIdx.x * blockDim.x + threadIdx.x;
  if (i >= n) return;
  float di = rsqrtf(1.0f + (float)(rowptr[i + 1] - rowptr[i]));
  dinv[i] = di;
  float3 v;
  v.x = di * x[3 * (size_t)i];
  v.y = di * x[3 * (size_t)i + 1];
  v.z = di * x[3 * (size_t)i + 2];
  *(float3*)(p1 + 3 * (size_t)i) = v;
}

// ---------- packed-row load/accumulate/store (RW floats per row) ----------
template <int RW> struct RowT;
template <> struct RowT<3> {
  using T = float3;   // 12B rows
  static __device__ inline T ld(const float* __restrict__ p) { return *(const float3*)p; }
  static __device__ inline void add(float* __restrict__ a, const T& v) {
    a[0] += v.x; a[1] += v.y; a[2] += v.z;
  }
  static __device__ inline void st(float* __restrict__ p, const float* __restrict__ a) {
    *(float3*)p = make_float3(a[0], a[1], a[2]);
  }
};
template <> struct RowT<6> {
  struct T { float2 a, b, c; };       // 24B rows, 8B-aligned
  static __device__ inline T ld(const float* __restrict__ p) {
    T t; t.a = *(const float2*)p; t.b = *(const float2*)(p + 2); t.c = *(const float2*)(p + 4);
    return t;
  }
  static __device__ inline void add(float* __restrict__ a, const T& v) {
    a[0] += v.a.x; a[1] += v.a.y; a[2] += v.b.x; a[3] += v.b.y; a[4] += v.c.x; a[5] += v.c.y;
  }
  static __device__ inline void st(float* __restrict__ p, const float* __restrict__ a) {
    *(float2*)(p)     = make_float2(a[0], a[1]);
    *(float2*)(p + 2) = make_float2(a[2], a[3]);
    *(float2*)(p + 4) = make_float2(a[4], a[5]);
  }
};
template <> struct RowT<12> {
  struct T { float4 a, b, c; };       // 48B rows, 16B-aligned bases
  static __device__ inline T ld(const float* __restrict__ p) {
    T t; t.a = *(const float4*)p; t.b = *(const float4*)(p + 4); t.c = *(const float4*)(p + 8);
    return t;
  }
  static __device__ inline void add(float* __restrict__ a, const T& v) {
    a[0] += v.a.x; a[1] += v.a.y; a[2] += v.a.z; a[3] += v.a.w;
    a[4] += v.b.x; a[5] += v.b.y; a[6] += v.b.z; a[7] += v.b.w;
    a[8] += v.c.x; a[9] += v.c.y; a[10] += v.c.z; a[11] += v.c.w;
  }
  static __device__ inline void st(float* __restrict__ p, const float* __restrict__ a) {
    *(float4*)(p)     = make_float4(a[0], a[1], a[2], a[3]);
    *(float4*)(p + 4) = make_float4(a[4], a[5], a[6], a[7]);
    *(float4*)(p + 8) = make_float4(a[8], a[9], a[10], a[11]);
  }
};

// ---------- slot-strided gather over [st,en), unroll UN, adj prefetch 1 ahead ----------
template <int RW, int UN>
__device__ inline void gather_p(const int* __restrict__ adj, int st, int en,
                                const float* __restrict__ pin, float* __restrict__ acc,
                                int slot) {
  using RT = RowT<RW>;
  using T = typename RT::T;
  int k = st + slot;
  if (k + (UN - 1) * S < en) {
    int a[UN];
#pragma unroll
    for (int u = 0; u < UN; ++u) a[u] = adj[k + u * S];
    for (;;) {
      int kn = k + UN * S;
      bool more = (kn + (UN - 1) * S < en);
      int b[UN];
#pragma unroll
      for (int u = 0; u < UN; ++u) b[u] = 0;
      if (more) {
#pragma unroll
        for (int u = 0; u < UN; ++u) b[u] = adj[kn + u * S];
      }
      T v[UN];
#pragma unroll
      for (int u = 0; u < UN; ++u) v[u] = RT::ld(pin + (size_t)a[u] * RW);
#pragma unroll
      for (int u = 0; u < UN; ++u) RT::add(acc, v[u]);
      k = kn;
      if (!more) break;
#pragma unroll
      for (int u = 0; u < UN; ++u) a[u] = b[u];
    }
  }
  for (; k < en; k += S) {
    T v = RT::ld(pin + (size_t)adj[k] * RW);
    RT::add(acc, v);
  }
}

// 4-lane butterfly: all lanes end with the full sum
template <int FIN>
__device__ inline void group_reduce(float* __restrict__ acc) {
#pragma unroll
  for (int j = 0; j < FIN; ++j) {
    acc[j] += __shfl_xor(acc[j], 1);
    acc[j] += __shfl_xor(acc[j], 2);
  }
}

// ---------- single-phase fused gather (layer 1 only; slab fits L2) ----------
template <int RW, int FOUT, int MODE>
__global__ void __launch_bounds__(BK, 8) k_gather_fused(
    const int* __restrict__ adj, const int* __restrict__ rowptr,
    const float* __restrict__ pin, const float* __restrict__ W,
    const float* __restrict__ bias, const float* __restrict__ dinv,
    float* __restrict__ pout, int n) {
  __shared__ float sW[RW * FOUT];
  __shared__ float sb[FOUT];
  for (int t = threadIdx.x; t < RW * FOUT; t += BK) sW[t] = W[t];
  if (threadIdx.x < FOUT) sb[threadIdx.x] = bias[threadIdx.x];
  __syncthreads();
  int g = blockIdx.x * blockDim.x + threadIdx.x;
  int i = g >> LOGS;
  int slot = g & (S - 1);
  if (i >= n) return;
  float acc[RW] = {};
  if (slot == 0) {                                  // self-loop on slot 0
    typename RowT<RW>::T v = RowT<RW>::ld(pin + (size_t)i * RW);
    RowT<RW>::add(acc, v);
  }
  gather_p<RW, 4>(adj, rowptr[i], rowptr[i + 1], pin, acc, slot);
  group_reduce<RW>(acc);
  float di = dinv[i];
  float h[FOUT];
  float ss = 0.f;
#pragma unroll
  for (int j = 0; j < FOUT; ++j) {
    float s = 0.f;
#pragma unroll
    for (int kk = 0; kk < RW; ++kk) s = fmaf(acc[kk], sW[kk * FOUT + j], s);
    float t = fmaf(di, s, sb[j]);
    h[j] = t;
    ss += t * t;
  }
  float o[FOUT];
  if (MODE == 0) {
#pragma unroll
    for (int j = 0; j < FOUT; ++j) o[j] = di * tanhf(h[j]);
  } else {
    float inv = 1.f / fmaxf(sqrtf(ss), 1e-12f);
#pragma unroll
    for (int j = 0; j < FOUT; ++j) o[j] = di * tanhf(h[j] * inv);
  }
  if (slot == 0) {
    float* po = pout + (size_t)i * FOUT;
    if (MODE == 0) {                                 // 24B rows: 3x float2
      *(float2*)(po)     = make_float2(o[0], o[1]);
      *(float2*)(po + 2) = make_float2(o[2], o[3]);
      *(float2*)(po + 4) = make_float2(o[4], o[5]);
    } else {                                         // 48B rows: 3x float4
      *(float4*)(po)     = make_float4(o[0], o[1], o[2], o[3]);
      *(float4*)(po + 4) = make_float4(o[4], o[5], o[6], o[7]);
      *(float4*)(po + 8) = make_float4(o[8], o[9], o[10], o[11]);
    }
  }
}

// ---------- phased gather: one src-range slab per kernel launch ----------
// FIRST: acc = self-loop; else acc = reload packed partial (slot 0 holds it).
template <int RW, bool FIRST>
__global__ void __launch_bounds__(BK, 8) k_gphase(
    const int* __restrict__ adj, const int* __restrict__ stA,
    const int* __restrict__ enB, const float* __restrict__ pin,
    float* __restrict__ accb, int n) {
  int g = blockIdx.x * blockDim.x + threadIdx.x;
  int i = g >> LOGS;
  int slot = g & (S - 1);
  if (i >= n) return;
  float acc[RW] = {};
  if (slot == 0) {
    if (FIRST) {
      typename RowT<RW>::T v = RowT<RW>::ld(pin + (size_t)i * RW);  // self-loop
      RowT<RW>::add(acc, v);
    } else {
      typename RowT<RW>::T v = RowT<RW>::ld(accb + (size_t)i * RW); // partial
      RowT<RW>::add(acc, v);
    }
  }
  gather_p<RW, 4>(adj, stA[i], enB[i], pin, acc, slot);
  group_reduce<RW>(acc);
  if (slot == 0) RowT<RW>::st(accb + (size_t)i * RW, acc);
}

// ---------- final phase: last slab + epilogue ----------
// MODE 1: l2norm+tanh -> pout (48B rows for FOUT=12)
// MODE 2: l2norm -> Wc -> l2norm -> out (13 floats)
template <int RW, int FOUT, int MODE>
__global__ void __launch_bounds__(BK, 6) k_gphase_last(
    const int* __restrict__ adj, const int* __restrict__ stA,
    const int* __restrict__ rowptr, const float* __restrict__ pin,
    const float* __restrict__ W, const float* __restrict__ bias,
    const float* __restrict__ Wc, const float* __restrict__ bc,
    const float* __restrict__ dinv, const float* __restrict__ accb,
    float* __restrict__ out, int n) {
  constexpr int FC = 13;
  __shared__ float sW[RW * FOUT];
  __shared__ float sb[FOUT];
  __shared__ float sWc[MODE == 2 ? FOUT * FC : 1];
  __shared__ float sbc[MODE == 2 ? FC : 1];
  for (int t = threadIdx.x; t < RW * FOUT; t += BK) sW[t] = W[t];
  if (threadIdx.x < FOUT) sb[threadIdx.x] = bias[threadIdx.x];
  if (MODE == 2) {
    for (int t = threadIdx.x; t < FOUT * FC; t += BK) sWc[t] = Wc[t];
    if (threadIdx.x < FC) sbc[threadIdx.x] = bc[threadIdx.x];
  }
  __syncthreads();
  int g = blockIdx.x * blockDim.x + threadIdx.x;
  int i = g >> LOGS;
  int slot = g & (S - 1);
  if (i >= n) return;
  float acc[RW] = {};
  if (slot == 0) {
    typename RowT<RW>::T v = RowT<RW>::ld(accb + (size_t)i * RW);   // partial
    RowT<RW>::add(acc, v);
  }
  gather_p<RW, 4>(adj, stA[i], rowptr[i + 1], pin, acc, slot);
  group_reduce<RW>(acc);
  float di = dinv[i];
  float h[FOUT];
  float ss = 0.f;
#pragma unroll
  for (int j = 0; j < FOUT; ++j) {
    float s = 0.f;
#pragma unroll
    for (int kk = 0; kk < RW; ++kk) s = fmaf(acc[kk], sW[kk * FOUT + j], s);
    float t = fmaf(di, s, sb[j]);
    h[j] = t;
    ss += t * t;
  }
  float inv = 1.f / fmaxf(sqrtf(ss), 1e-12f);
  if (MODE == 1) {
    float o[FOUT];
#pragma unroll
    for (int j = 0; j < FOUT; ++j) o[j] = di * tanhf(h[j] * inv);
    if (slot == 0) {
      float* po = out + (size_t)i * FOUT;                  // 48B rows (FOUT=12)
      *(float4*)(po)     = make_float4(o[0], o[1], o[2], o[3]);
      *(float4*)(po + 4) = make_float4(o[4], o[5], o[6], o[7]);
      *(float4*)(po + 8) = make_float4(o[8], o[9], o[10], o[11]);
    }
  } else {
    float v[FC];
    float ss2 = 0.f;
#pragma unroll
    for (int j = 0; j < FC; ++j) {
      float s = sbc[j];
#pragma unroll
      for (int kk = 0; kk < FOUT; ++kk) s = fmaf(h[kk] * inv, sWc[kk * FC + j], s);
      v[j] = s;
      ss2 += s * s;
    }
    float inv2 = 1.f / fmaxf(sqrtf(ss2), 1e-12f);
    if (slot == 0) {
#pragma unroll
      for (int j = 0; j < FC; ++j) out[(size_t)i * FC + j] = v[j] * inv2;
    }
  }
}

extern "C" void kernel_launch(void* const* d_in, const int* in_sizes, int n_in,
                              void* d_out, int out_size, void* d_ws, size_t ws_size,
                              hipStream_t stream) {
  const float* x  = (const float*)d_in[0];
  const int*   ei = (const int*)d_in[1];
  const float* W1 = (const float*)d_in[2];
  const float* b1 = (const float*)d_in[3];
  const float* W2 = (const float*)d_in[4];
  const float* b2 = (const float*)d_in[5];
  const float* W3 = (const float*)d_in[6];
  const float* b3 = (const float*)d_in[7];
  const float* Wc = (const float*)d_in[8];
  const float* bc = (const float*)d_in[9];
  float* out = (float*)d_out;

  const int n = NN;
  const int e = NE;
  const int* srcI = ei;       // row 0
  const int* dstI = ei + e;   // row 1

  // Workspace (words):
  //   dinv[N] | rowptr[N+8] | sbase[512] | tot[512] | hist[NBA*NBL] | adj[E]
  //   | b8[N] | b13[N] | b17[N] | pad->64B | R
  // R hosts dense stg[E]=6.4M words during build, then
  //   p1[3N] | p2[6N] | p3[12N] | accb[12N] (=6.6M words) during gathers.
  // hist = 391*1024 = 400384 words (1.6MB). Total ~= 58 MB (<=76 MB proven).
  float* ws = (float*)d_ws;
  float* dinv  = ws;
  int* rowptr  = (int*)(ws + n);            // N+8 (uses N+1, padded)
  int* sbase   = rowptr + n + 8;            // NBA+1 used
  int* tot     = sbase + 512;
  int* hist    = tot + 512;                 // NBA * NBL (16B-aligned)
  int* adj     = hist + NBA * NBL;
  int* b8      = adj + e;
  int* b13     = b8 + n;
  int* b17     = b13 + n;
  size_t roff = (size_t)n + (n + 8) + 512 + 512 + (size_t)NBA * NBL + e + 3 * (size_t)n;
  roff = (roff + 15) & ~(size_t)15;         // round to 16 words = 64B
  float* R     = ws + roff;
  unsigned* stg = (unsigned*)R;             // dense E words during build
  float* p1   = R;                          // 3N
  float* p2   = R + (size_t)3 * n;          // 6N
  float* p3   = R + (size_t)9 * n;          // 12N
  float* accb = R + (size_t)21 * n;         // 12N packed partials (16B-aligned)

  const int gn  = (n + BK - 1) / BK;
  const int gnS = (n * S + BK - 1) / BK;    // 3125 blocks

  // --- CSR build: count -> scan -> block-private scatter -> quarter-bin build ---
  k_count<<<NBL, BKC, 0, stream>>>(dstI, hist, e);
  k_scanrow<<<NBA, 256, 0, stream>>>(hist, tot);
  k_scanbin<<<1, 512, 0, stream>>>(tot, sbase);
  k_scat<<<NBL, BKC, 0, stream>>>(srcI, dstI, hist, sbase, stg, e);
  k_build<<<NBB, BKB, 0, stream>>>(stg, sbase, rowptr, adj, b8, b13, b17);

  // --- dinv + p1 = dinv * x (12B rows) ---
  k_prep<<<gn, BK, 0, stream>>>(x, rowptr, dinv, p1, n);

  // --- Layer 1 (p1 = 2.4 MB, fits per-XCD L2): single fused phase ---
  k_gather_fused<3, 6, 0><<<gnS, BK, 0, stream>>>(adj, rowptr, p1, W1, b1, dinv, p2, n);

  // --- Layer 2 (p2 = 4.8 MB): 2 phases, cut at bucket 13 ---
  k_gphase<6, true><<<gnS, BK, 0, stream>>>(adj, rowptr, b13, p2, accb, n);
  k_gphase_last<6, 12, 1><<<gnS, BK, 0, stream>>>(adj, b13, rowptr, p2, W2, b2,
                                                  Wc, bc, dinv, accb, p3, n);

  // --- Layer 3 + classifier (p3 = 9.6 MB): 3 phases, cuts at buckets 8/17 ---
  k_gphase<12, true><<<gnS, BK, 0, stream>>>(adj, rowptr, b8, p3, accb, n);
  k_gphase<12, false><<<gnS, BK, 0, stream>>>(adj, b8, b17, p3, accb, n);
  k_gphase_last<12, 24, 2><<<gnS, BK, 0, stream>>>(adj, b17, rowptr, p3, W3, b3,
                                                   Wc, bc, dinv, accb, out, n);
}

// Round 11
// 389.317 us; speedup vs baseline: 1.1991x; 1.1038x over previous
//
#include <hip/hip_runtime.h>
#include <math.h>

// GCN on MI355X. N=200000 nodes, E=6400000 edges.
// R25: R24 won (467->430; k_build fixed at high occ). New #1 k_scat 81us:
// WRITE 82.5MB = 3.2x amp -- per-(bin,block) subranges are ~16 entries (64B)
// whose 4B stores land scattered in time -> partial-line writebacks at ~1TB/s.
// Cure = same as k_build's: stage the block's 6250 recs in LDS (lstg), flush
// per-bin contiguous runs (thread t<391 copies its bin's run; same-thread
// consecutive stores form full lines -> amp ~1). Local per-bin counts come
// FREE from hist deltas (hist[b][blk+1]-hist[b][blk], tot for last block) --
// no recount. LDS 32.2KB -> still 4 blk/CU (wave-capped). NE=1024*6250 exact.
// Pre-commit: if k_scat >=60us with ~28MB writes, the LDS-atomic-return chain
// is the sort's floor -> stop tuning build, pivot to gathers.
// Everything else identical to R24. MESSAGES STAY FP32 (R7: bf16 fails 0.21).

static constexpr int NN = 200000;
static constexpr int NE = 6400000;
static constexpr int BK = 256;

static constexpr int SUBW  = 512;                    // scat/count bin width (d>>9)
static constexpr int NBA   = (NN + SUBW - 1) / SUBW; // 391 bins
static constexpr int QDS   = 128;                    // dsts per build quarter
static constexpr int BKB   = 512;                    // build threads
static constexpr int NBB   = ((NBA + 7) / 8) * 8 * 4;// 1568 swizzled build blocks
static constexpr int LCAP  = 4864;                   // quarter staging cap (+12 sigma)
static constexpr int NBL   = 1024;                   // count/scatter blocks
static constexpr int BKC   = 512;                    // threads in count/scatter
static constexpr int SEG   = (NE + NBL - 1) / NBL;   // 6250 edges per block (exact)
static constexpr int SRCSH = 13;                     // src-bucket shift (8K nodes)
static constexpr int NSB   = (NN + (1 << SRCSH) - 1) >> SRCSH;  // 25 buckets

static constexpr int S     = 4;                      // lanes per node in gathers
static constexpr int LOGS  = 2;

// ---------- build pass 1: per-block LDS histogram (no return deps) ----------
__global__ void __launch_bounds__(BKC) k_count(const int* __restrict__ dstI,
                                               int* __restrict__ hist, int e) {
  __shared__ int cnt[NBA];
  for (int t = threadIdx.x; t < NBA; t += BKC) cnt[t] = 0;
  __syncthreads();
  int blk = blockIdx.x;
  int st = blk * SEG, en = st + SEG; if (en > e) en = e;
  int i = st + (int)threadIdx.x;
  for (; i + 3 * BKC < en; i += 4 * BKC) {
    int d0 = __builtin_nontemporal_load(dstI + i);
    int d1 = __builtin_nontemporal_load(dstI + i + BKC);
    int d2 = __builtin_nontemporal_load(dstI + i + 2 * BKC);
    int d3 = __builtin_nontemporal_load(dstI + i + 3 * BKC);
    atomicAdd(&cnt[d0 >> 9], 1);
    atomicAdd(&cnt[d1 >> 9], 1);
    atomicAdd(&cnt[d2 >> 9], 1);
    atomicAdd(&cnt[d3 >> 9], 1);
  }
  for (; i < en; i += BKC) {
    int d = __builtin_nontemporal_load(dstI + i);
    atomicAdd(&cnt[d >> 9], 1);
  }
  __syncthreads();
  for (int t = threadIdx.x; t < NBA; t += BKC) hist[(size_t)t * NBL + blk] = cnt[t];
}

// ---------- build pass 2a: per-bin exclusive scan over 1024 blocks ----------
__global__ void __launch_bounds__(256) k_scanrow(int* __restrict__ hist,
                                                 int* __restrict__ tot) {
  __shared__ int s0[256], s1[256];
  int b = blockIdx.x, t = threadIdx.x;
  int* row = hist + (size_t)b * NBL;
  uint4 vv = ((const uint4*)row)[t];           // row 16B-aligned (NBL%4==0)
  int v0 = (int)vv.x, v1 = (int)vv.y, v2 = (int)vv.z, v3 = (int)vv.w;
  int s = v0 + v1 + v2 + v3;
  s0[t] = s;
  __syncthreads();
  int* a = s0; int* bb = s1;
  for (int o = 1; o < 256; o <<= 1) {
    bb[t] = a[t] + ((t >= o) ? a[t - o] : 0);
    __syncthreads();
    int* tmp = a; a = bb; bb = tmp;
  }
  int ex = a[t] - s;                 // exclusive over quads
  uint4 w;
  w.x = (unsigned)ex;
  w.y = (unsigned)(ex + v0);
  w.z = (unsigned)(ex + v0 + v1);
  w.w = (unsigned)(ex + v0 + v1 + v2);
  ((uint4*)row)[t] = w;
  if (t == 255) tot[b] = a[t];
}

// ---------- build pass 2b: exclusive scan of bin totals -> dense bases ----------
__global__ void k_scanbin(const int* __restrict__ tot, int* __restrict__ sbase) {
  __shared__ int s0[512], s1[512];
  int t = threadIdx.x;
  int v = (t < NBA) ? tot[t] : 0;
  s0[t] = v;
  __syncthreads();
  int* a = s0; int* b = s1;
  for (int o = 1; o < 512; o <<= 1) {
    b[t] = a[t] + ((t >= o) ? a[t - o] : 0);
    __syncthreads();
    int* tmp = a; a = b; b = tmp;
  }
  if (t < NBA) sbase[t] = a[t] - v;
  if (t == NBA - 1) sbase[NBA] = a[t];   // == E
}

// ---------- build pass 3: LDS-staged scatter, per-bin coalesced-run flush ----------
// Local per-bin counts = hist deltas (free). Records land in lstg (LDS) via
// cursor atomics; flush copies each bin's run contiguously -> full lines.
__global__ void __launch_bounds__(BKC) k_scat(const int* __restrict__ srcI,
                                              const int* __restrict__ dstI,
                                              const int* __restrict__ hist,
                                              const int* __restrict__ tot,
                                              const int* __restrict__ sbase,
                                              unsigned* __restrict__ stg, int e) {
  __shared__ int pref[NBA];
  __shared__ int cur[NBA];
  __shared__ unsigned lstg[SEG];
  __shared__ int s0[BKC], s1[BKC];
  int blk = blockIdx.x;
  int t = threadIdx.x;
  int h0 = 0, lc = 0;
  if (t < NBA) {
    h0 = hist[(size_t)t * NBL + blk];
    int h1 = (blk < NBL - 1) ? hist[(size_t)t * NBL + blk + 1] : tot[t];
    lc = h1 - h0;
  }
  s0[t] = lc;
  __syncthreads();
  int* a = s0; int* b = s1;
  for (int o = 1; o < BKC; o <<= 1) {
    b[t] = a[t] + ((t >= o) ? a[t - o] : 0);
    __syncthreads();
    int* tmp = a; a = b; b = tmp;
  }
  if (t < NBA) {
    int ex = a[t] - lc;
    pref[t] = ex;
    cur[t] = ex;
  }
  __syncthreads();
  int st = blk * SEG, en = st + SEG; if (en > e) en = e;
  int i = st + t;
  for (; i + 3 * BKC < en; i += 4 * BKC) {
    int s0v = __builtin_nontemporal_load(srcI + i);
    int d0 = __builtin_nontemporal_load(dstI + i);
    int s1v = __builtin_nontemporal_load(srcI + i + BKC);
    int d1 = __builtin_nontemporal_load(dstI + i + BKC);
    int s2v = __builtin_nontemporal_load(srcI + i + 2 * BKC);
    int d2 = __builtin_nontemporal_load(dstI + i + 2 * BKC);
    int s3v = __builtin_nontemporal_load(srcI + i + 3 * BKC);
    int d3 = __builtin_nontemporal_load(dstI + i + 3 * BKC);
    int p0 = atomicAdd(&cur[d0 >> 9], 1);
    int p1 = atomicAdd(&cur[d1 >> 9], 1);
    int p2 = atomicAdd(&cur[d2 >> 9], 1);
    int p3 = atomicAdd(&cur[d3 >> 9], 1);
    lstg[p0] = ((unsigned)(d0 & (SUBW - 1)) << 18) | (unsigned)s0v;
    lstg[p1] = ((unsigned)(d1 & (SUBW - 1)) << 18) | (unsigned)s1v;
    lstg[p2] = ((unsigned)(d2 & (SUBW - 1)) << 18) | (unsigned)s2v;
    lstg[p3] = ((unsigned)(d3 & (SUBW - 1)) << 18) | (unsigned)s3v;
  }
  for (; i < en; i += BKC) {
    int sv = __builtin_nontemporal_load(srcI + i);
    int d = __builtin_nontemporal_load(dstI + i);
    int p = atomicAdd(&cur[d >> 9], 1);
    lstg[p] = ((unsigned)(d & (SUBW - 1)) << 18) | (unsigned)sv;
  }
  __syncthreads();
  // flush: thread t copies bin t's run; same-thread consecutive stores merge
  if (t < NBA && lc > 0) {
    int lo = pref[t];
    int g = sbase[t] + h0;
    for (int j = 0; j < lc; ++j) stg[g + j] = lstg[lo + j];
  }
}

// ---------- pass 4: quarter-bin ordered build, LDS-staged coalesced flush ----------
// XCD-swizzled: quarters of one bin share an XCD (8 apart in dispatch) so the
// bin's ~16KB stg slab is L2-hot for quarters 1-3. Quarter q's base offset =
// bin base + (# earlier-quarter recs), tallied during the hist read.
__global__ void __launch_bounds__(BKB) k_build(const unsigned* __restrict__ stg,
                                               const int* __restrict__ sbase,
                                               int* __restrict__ rowptr,
                                               int* __restrict__ adj,
                                               int* __restrict__ b8,
                                               int* __restrict__ b13,
                                               int* __restrict__ b17) {
  __shared__ unsigned hist2[QDS * NSB];    // 12.8 KB: [dl_q][sb]
  __shared__ int htot[QDS];
  __shared__ int s0[QDS], s1[QDS];
  __shared__ unsigned astg[LCAP];          // 19.5 KB staged adj (total ~34KB)
  __shared__ int beforeCnt;
  int g = blockIdx.x;
  int x = g & 7, j = g >> 3;
  int q = j & 3;
  int bin = (j >> 2) * 8 + x;              // quarters of bin -> same XCD (g%8)
  if (bin >= NBA) return;
  int base = sbase[bin];
  int m = sbase[bin + 1] - base;
  size_t off = (size_t)base;
  if (g == 0 && threadIdx.x == 0) rowptr[NN] = sbase[NBA];   // == E
  for (int t = threadIdx.x; t < QDS * NSB; t += BKB) hist2[t] = 0;
  if (threadIdx.x == 0) beforeCnt = 0;
  __syncthreads();
  // read 1: histogram this quarter; count earlier-quarter recs for base_eff
  int myBefore = 0;
  for (int k = threadIdx.x; k < m; k += BKB) {
    unsigned rec = stg[off + k];
    int dl = (int)(rec >> 18);
    int dq = dl >> 7;
    if (dq == q) {
      int sb = (int)((rec & 0x3FFFFu) >> SRCSH);
      atomicAdd(&hist2[(dl & (QDS - 1)) * NSB + sb], 1u);
    } else if (dq < q) {
      ++myBefore;
    }
  }
  if (myBefore) atomicAdd(&beforeCnt, myBefore);
  __syncthreads();
  // per-dl exclusive scan over sb (threads 0..127; stride 25 spreads banks)
  if (threadIdx.x < QDS) {
    int dl = threadIdx.x;
    unsigned run = 0;
    for (int sb = 0; sb < NSB; ++sb) {
      unsigned c = hist2[dl * NSB + sb];
      hist2[dl * NSB + sb] = run;
      run += c;
    }
    htot[dl] = (int)run;
    s0[dl] = (int)run;
  }
  __syncthreads();
  // block inclusive scan over 128 dls (ping-pong, 7 iters)
  int* a = s0; int* bb = s1;
  for (int o2 = 1; o2 < QDS; o2 <<= 1) {
    if (threadIdx.x < QDS) {
      int t = threadIdx.x;
      bb[t] = a[t] + ((t >= o2) ? a[t - o2] : 0);
    }
    __syncthreads();
    int* tmp = a; a = bb; bb = tmp;
  }
  int mytot = a[QDS - 1];
  int base_eff = base + beforeCnt;
  if (threadIdx.x < QDS) {
    int t = threadIdx.x;
    int node = bin * SUBW + q * QDS + t;
    int ex = a[t] - htot[t];
    if (node < NN) {
      rowptr[node] = base_eff + ex;
      b8[node]  = base_eff + ex + (int)hist2[t * NSB + 8];   // exclusive prefix
      b13[node] = base_eff + ex + (int)hist2[t * NSB + 13];
      b17[node] = base_eff + ex + (int)hist2[t * NSB + 17];
    }
    bb[t] = ex;
  }
  __syncthreads();
  // read 2 (L2-hot): ordered scatter into LDS staging (overflow -> direct)
  for (int k = threadIdx.x; k < m; k += BKB) {
    unsigned rec = stg[off + k];
    int dl = (int)(rec >> 18);
    if ((dl >> 7) != q) continue;
    unsigned src = rec & 0x3FFFFu;
    int sb = (int)(src >> SRCSH);
    int p = bb[dl & (QDS - 1)] + (int)atomicAdd(&hist2[(dl & (QDS - 1)) * NSB + sb], 1u);
    if (p < LCAP) astg[p] = src;
    else adj[base_eff + p] = (int)src;
  }
  __syncthreads();
  // coalesced flush: zero write amplification
  int mm = mytot < LCAP ? mytot : LCAP;
  for (int k = threadIdx.x; k < mm; k += BKB) adj[base_eff + k] = (int)astg[k];
}

// dinv + p1 = dinv*x in one pass (12B rows)
__global__ void k_prep(const float* __restrict__ x, const int* __restrict__ rowptr,
                       float* __restrict__ dinv, float* __restrict__ p1, int n) {
  int i = blockIdx.x * blockDim.x + threadIdx.x;
  if (i >= n) return;
  float di = rsqrtf(1.0f + (float)(rowptr[i + 1] - rowptr[i]));
  dinv[i] = di;
  float3 v;
  v.x = di * x[3 * (size_t)i];
  v.y = di * x[3 * (size_t)i + 1];
  v.z = di * x[3 * (size_t)i + 2];
  *(float3*)(p1 + 3 * (size_t)i) = v;
}

// ---------- packed-row load/accumulate/store (RW floats per row) ----------
template <int RW> struct RowT;
template <> struct RowT<3> {
  using T = float3;   // 12B rows
  static __device__ inline T ld(const float* __restrict__ p) { return *(const float3*)p; }
  static __device__ inline void add(float* __restrict__ a, const T& v) {
    a[0] += v.x; a[1] += v.y; a[2] += v.z;
  }
  static __device__ inline void st(float* __restrict__ p, const float* __restrict__ a) {
    *(float3*)p = make_float3(a[0], a[1], a[2]);
  }
};
template <> struct RowT<6> {
  struct T { float2 a, b, c; };       // 24B rows, 8B-aligned
  static __device__ inline T ld(const float* __restrict__ p) {
    T t; t.a = *(const float2*)p; t.b = *(const float2*)(p + 2); t.c = *(const float2*)(p + 4);
    return t;
  }
  static __device__ inline void add(float* __restrict__ a, const T& v) {
    a[0] += v.a.x; a[1] += v.a.y; a[2] += v.b.x; a[3] += v.b.y; a[4] += v.c.x; a[5] += v.c.y;
  }
  static __device__ inline void st(float* __restrict__ p, const float* __restrict__ a) {
    *(float2*)(p)     = make_float2(a[0], a[1]);
    *(float2*)(p + 2) = make_float2(a[2], a[3]);
    *(float2*)(p + 4) = make_float2(a[4], a[5]);
  }
};
template <> struct RowT<12> {
  struct T { float4 a, b, c; };       // 48B rows, 16B-aligned bases
  static __device__ inline T ld(const float* __restrict__ p) {
    T t; t.a = *(const float4*)p; t.b = *(const float4*)(p + 4); t.c = *(const float4*)(p + 8);
    return t;
  }
  static __device__ inline void add(float* __restrict__ a, const T& v) {
    a[0] += v.a.x; a[1] += v.a.y; a[2] += v.a.z; a[3] += v.a.w;
    a[4] += v.b.x; a[5] += v.b.y; a[6] += v.b.z; a[7] += v.b.w;
    a[8] += v.c.x; a[9] += v.c.y; a[10] += v.c.z; a[11] += v.c.w;
  }
  static __device__ inline void st(float* __restrict__ p, const float* __restrict__ a) {
    *(float4*)(p)     = make_float4(a[0], a[1], a[2], a[3]);
    *(float4*)(p + 4) = make_float4(a[4], a[5], a[6], a[7]);
    *(float4*)(p + 8) = make_float4(a[8], a[9], a[10], a[11]);
  }
};

// ---------- slot-strided gather over [st,en), unroll UN, adj prefetch 1 ahead ----------
template <int RW, int UN>
__device__ inline void gather_p(const int* __restrict__ adj, int st, int en,
                                const float* __restrict__ pin, float* __restrict__ acc,
                                int slot) {
  using RT = RowT<RW>;
  using T = typename RT::T;
  int k = st + slot;
  if (k + (UN - 1) * S < en) {
    int a[UN];
#pragma unroll
    for (int u = 0; u < UN; ++u) a[u] = adj[k + u * S];
    for (;;) {
      int kn = k + UN * S;
      bool more = (kn + (UN - 1) * S < en);
      int b[UN];
#pragma unroll
      for (int u = 0; u < UN; ++u) b[u] = 0;
      if (more) {
#pragma unroll
        for (int u = 0; u < UN; ++u) b[u] = adj[kn + u * S];
      }
      T v[UN];
#pragma unroll
      for (int u = 0; u < UN; ++u) v[u] = RT::ld(pin + (size_t)a[u] * RW);
#pragma unroll
      for (int u = 0; u < UN; ++u) RT::add(acc, v[u]);
      k = kn;
      if (!more) break;
#pragma unroll
      for (int u = 0; u < UN; ++u) a[u] = b[u];
    }
  }
  for (; k < en; k += S) {
    T v = RT::ld(pin + (size_t)adj[k] * RW);
    RT::add(acc, v);
  }
}

// 4-lane butterfly: all lanes end with the full sum
template <int FIN>
__device__ inline void group_reduce(float* __restrict__ acc) {
#pragma unroll
  for (int j = 0; j < FIN; ++j) {
    acc[j] += __shfl_xor(acc[j], 1);
    acc[j] += __shfl_xor(acc[j], 2);
  }
}

// ---------- single-phase fused gather (layer 1 only; slab fits L2) ----------
template <int RW, int FOUT, int MODE>
__global__ void __launch_bounds__(BK, 8) k_gather_fused(
    const int* __restrict__ adj, const int* __restrict__ rowptr,
    const float* __restrict__ pin, const float* __restrict__ W,
    const float* __restrict__ bias, const float* __restrict__ dinv,
    float* __restrict__ pout, int n) {
  __shared__ float sW[RW * FOUT];
  __shared__ float sb[FOUT];
  for (int t = threadIdx.x; t < RW * FOUT; t += BK) sW[t] = W[t];
  if (threadIdx.x < FOUT) sb[threadIdx.x] = bias[threadIdx.x];
  __syncthreads();
  int g = blockIdx.x * blockDim.x + threadIdx.x;
  int i = g >> LOGS;
  int slot = g & (S - 1);
  if (i >= n) return;
  float acc[RW] = {};
  if (slot == 0) {                                  // self-loop on slot 0
    typename RowT<RW>::T v = RowT<RW>::ld(pin + (size_t)i * RW);
    RowT<RW>::add(acc, v);
  }
  gather_p<RW, 4>(adj, rowptr[i], rowptr[i + 1], pin, acc, slot);
  group_reduce<RW>(acc);
  float di = dinv[i];
  float h[FOUT];
  float ss = 0.f;
#pragma unroll
  for (int j = 0; j < FOUT; ++j) {
    float s = 0.f;
#pragma unroll
    for (int kk = 0; kk < RW; ++kk) s = fmaf(acc[kk], sW[kk * FOUT + j], s);
    float t = fmaf(di, s, sb[j]);
    h[j] = t;
    ss += t * t;
  }
  float o[FOUT];
  if (MODE == 0) {
#pragma unroll
    for (int j = 0; j < FOUT; ++j) o[j] = di * tanhf(h[j]);
  } else {
    float inv = 1.f / fmaxf(sqrtf(ss), 1e-12f);
#pragma unroll
    for (int j = 0; j < FOUT; ++j) o[j] = di * tanhf(h[j] * inv);
  }
  if (slot == 0) {
    float* po = pout + (size_t)i * FOUT;
    if (MODE == 0) {                                 // 24B rows: 3x float2
      *(float2*)(po)     = make_float2(o[0], o[1]);
      *(float2*)(po + 2) = make_float2(o[2], o[3]);
      *(float2*)(po + 4) = make_float2(o[4], o[5]);
    } else {                                         // 48B rows: 3x float4
      *(float4*)(po)     = make_float4(o[0], o[1], o[2], o[3]);
      *(float4*)(po + 4) = make_float4(o[4], o[5], o[6], o[7]);
      *(float4*)(po + 8) = make_float4(o[8], o[9], o[10], o[11]);
    }
  }
}

// ---------- phased gather: one src-range slab per kernel launch ----------
// FIRST: acc = self-loop; else acc = reload packed partial (slot 0 holds it).
template <int RW, bool FIRST>
__global__ void __launch_bounds__(BK, 8) k_gphase(
    const int* __restrict__ adj, const int* __restrict__ stA,
    const int* __restrict__ enB, const float* __restrict__ pin,
    float* __restrict__ accb, int n) {
  int g = blockIdx.x * blockDim.x + threadIdx.x;
  int i = g >> LOGS;
  int slot = g & (S - 1);
  if (i >= n) return;
  float acc[RW] = {};
  if (slot == 0) {
    if (FIRST) {
      typename RowT<RW>::T v = RowT<RW>::ld(pin + (size_t)i * RW);  // self-loop
      RowT<RW>::add(acc, v);
    } else {
      typename RowT<RW>::T v = RowT<RW>::ld(accb + (size_t)i * RW); // partial
      RowT<RW>::add(acc, v);
    }
  }
  gather_p<RW, 4>(adj, stA[i], enB[i], pin, acc, slot);
  group_reduce<RW>(acc);
  if (slot == 0) RowT<RW>::st(accb + (size_t)i * RW, acc);
}

// ---------- final phase: last slab + epilogue ----------
// MODE 1: l2norm+tanh -> pout (48B rows for FOUT=12)
// MODE 2: l2norm -> Wc -> l2norm -> out (13 floats)
template <int RW, int FOUT, int MODE>
__global__ void __launch_bounds__(BK, 6) k_gphase_last(
    const int* __restrict__ adj, const int* __restrict__ stA,
    const int* __restrict__ rowptr, const float* __restrict__ pin,
    const float* __restrict__ W, const float* __restrict__ bias,
    const float* __restrict__ Wc, const float* __restrict__ bc,
    const float* __restrict__ dinv, const float* __restrict__ accb,
    float* __restrict__ out, int n) {
  constexpr int FC = 13;
  __shared__ float sW[RW * FOUT];
  __shared__ float sb[FOUT];
  __shared__ float sWc[MODE == 2 ? FOUT * FC : 1];
  __shared__ float sbc[MODE == 2 ? FC : 1];
  for (int t = threadIdx.x; t < RW * FOUT; t += BK) sW[t] = W[t];
  if (threadIdx.x < FOUT) sb[threadIdx.x] = bias[threadIdx.x];
  if (MODE == 2) {
    for (int t = threadIdx.x; t < FOUT * FC; t += BK) sWc[t] = Wc[t];
    if (threadIdx.x < FC) sbc[threadIdx.x] = bc[threadIdx.x];
  }
  __syncthreads();
  int g = blockIdx.x * blockDim.x + threadIdx.x;
  int i = g >> LOGS;
  int slot = g & (S - 1);
  if (i >= n) return;
  float acc[RW] = {};
  if (slot == 0) {
    typename RowT<RW>::T v = RowT<RW>::ld(accb + (size_t)i * RW);   // partial
    RowT<RW>::add(acc, v);
  }
  gather_p<RW, 4>(adj, stA[i], rowptr[i + 1], pin, acc, slot);
  group_reduce<RW>(acc);
  float di = dinv[i];
  float h[FOUT];
  float ss = 0.f;
#pragma unroll
  for (int j = 0; j < FOUT; ++j) {
    float s = 0.f;
#pragma unroll
    for (int kk = 0; kk < RW; ++kk) s = fmaf(acc[kk], sW[kk * FOUT + j], s);
    float t = fmaf(di, s, sb[j]);
    h[j] = t;
    ss += t * t;
  }
  float inv = 1.f / fmaxf(sqrtf(ss), 1e-12f);
  if (MODE == 1) {
    float o[FOUT];
#pragma unroll
    for (int j = 0; j < FOUT; ++j) o[j] = di * tanhf(h[j] * inv);
    if (slot == 0) {
      float* po = out + (size_t)i * FOUT;                  // 48B rows (FOUT=12)
      *(float4*)(po)     = make_float4(o[0], o[1], o[2], o[3]);
      *(float4*)(po + 4) = make_float4(o[4], o[5], o[6], o[7]);
      *(float4*)(po + 8) = make_float4(o[8], o[9], o[10], o[11]);
    }
  } else {
    float v[FC];
    float ss2 = 0.f;
#pragma unroll
    for (int j = 0; j < FC; ++j) {
      float s = sbc[j];
#pragma unroll
      for (int kk = 0; kk < FOUT; ++kk) s = fmaf(h[kk] * inv, sWc[kk * FC + j], s);
      v[j] = s;
      ss2 += s * s;
    }
    float inv2 = 1.f / fmaxf(sqrtf(ss2), 1e-12f);
    if (slot == 0) {
#pragma unroll
      for (int j = 0; j < FC; ++j) out[(size_t)i * FC + j] = v[j] * inv2;
    }
  }
}

extern "C" void kernel_launch(void* const* d_in, const int* in_sizes, int n_in,
                              void* d_out, int out_size, void* d_ws, size_t ws_size,
                              hipStream_t stream) {
  const float* x  = (const float*)d_in[0];
  const int*   ei = (const int*)d_in[1];
  const float* W1 = (const float*)d_in[2];
  const float* b1 = (const float*)d_in[3];
  const float* W2 = (const float*)d_in[4];
  const float* b2 = (const float*)d_in[5];
  const float* W3 = (const float*)d_in[6];
  const float* b3 = (const float*)d_in[7];
  const float* Wc = (const float*)d_in[8];
  const float* bc = (const float*)d_in[9];
  float* out = (float*)d_out;

  const int n = NN;
  const int e = NE;
  const int* srcI = ei;       // row 0
  const int* dstI = ei + e;   // row 1

  // Workspace (words):
  //   dinv[N] | rowptr[N+8] | sbase[512] | tot[512] | hist[NBA*NBL] | adj[E]
  //   | b8[N] | b13[N] | b17[N] | pad->64B | R
  // R hosts dense stg[E]=6.4M words during build, then
  //   p1[3N] | p2[6N] | p3[12N] | accb[12N] (=6.6M words) during gathers.
  // hist = 391*1024 = 400384 words (1.6MB). Total ~= 58 MB (<=76 MB proven).
  float* ws = (float*)d_ws;
  float* dinv  = ws;
  int* rowptr  = (int*)(ws + n);            // N+8 (uses N+1, padded)
  int* sbase   = rowptr + n + 8;            // NBA+1 used
  int* tot     = sbase + 512;
  int* hist    = tot + 512;                 // NBA * NBL (16B-aligned)
  int* adj     = hist + NBA * NBL;
  int* b8      = adj + e;
  int* b13     = b8 + n;
  int* b17     = b13 + n;
  size_t roff = (size_t)n + (n + 8) + 512 + 512 + (size_t)NBA * NBL + e + 3 * (size_t)n;
  roff = (roff + 15) & ~(size_t)15;         // round to 16 words = 64B
  float* R     = ws + roff;
  unsigned* stg = (unsigned*)R;             // dense E words during build
  float* p1   = R;                          // 3N
  float* p2   = R + (size_t)3 * n;          // 6N
  float* p3   = R + (size_t)9 * n;          // 12N
  float* accb = R + (size_t)21 * n;         // 12N packed partials (16B-aligned)

  const int gn  = (n + BK - 1) / BK;
  const int gnS = (n * S + BK - 1) / BK;    // 3125 blocks

  // --- CSR build: count -> scan -> LDS-staged scatter -> quarter-bin build ---
  k_count<<<NBL, BKC, 0, stream>>>(dstI, hist, e);
  k_scanrow<<<NBA, 256, 0, stream>>>(hist, tot);
  k_scanbin<<<1, 512, 0, stream>>>(tot, sbase);
  k_scat<<<NBL, BKC, 0, stream>>>(srcI, dstI, hist, tot, sbase, stg, e);
  k_build<<<NBB, BKB, 0, stream>>>(stg, sbase, rowptr, adj, b8, b13, b17);

  // --- dinv + p1 = dinv * x (12B rows) ---
  k_prep<<<gn, BK, 0, stream>>>(x, rowptr, dinv, p1, n);

  // --- Layer 1 (p1 = 2.4 MB, fits per-XCD L2): single fused phase ---
  k_gather_fused<3, 6, 0><<<gnS, BK, 0, stream>>>(adj, rowptr, p1, W1, b1, dinv, p2, n);

  // --- Layer 2 (p2 = 4.8 MB): 2 phases, cut at bucket 13 ---
  k_gphase<6, true><<<gnS, BK, 0, stream>>>(adj, rowptr, b13, p2, accb, n);
  k_gphase_last<6, 12, 1><<<gnS, BK, 0, stream>>>(adj, b13, rowptr, p2, W2, b2,
                                                  Wc, bc, dinv, accb, p3, n);

  // --- Layer 3 + classifier (p3 = 9.6 MB): 3 phases, cuts at buckets 8/17 ---
  k_gphase<12, true><<<gnS, BK, 0, stream>>>(adj, rowptr, b8, p3, accb, n);
  k_gphase<12, false><<<gnS, BK, 0, stream>>>(adj, b8, b17, p3, accb, n);
  k_gphase_last<12, 24, 2><<<gnS, BK, 0, stream>>>(adj, b17, rowptr, p3, W3, b3,
                                                   Wc, bc, dinv, accb, out, n);
}

// Round 12
// 387.350 us; speedup vs baseline: 1.2052x; 1.0051x over previous
//
#include <hip/hip_runtime.h>
#include <math.h>

// GCN on MI355X. N=200000 nodes, E=6400000 edges.
// R26: R25 won (430->389). k_build 55.5us is now VALU/LDS-work-bound on
// REDUNDANT DECODE (4x read of each bin slab, 25-bucket hist per record;
// FETCH 16MB / WRITE 28MB say memory is fine). Two composing fixes:
//  (a) 25 buckets -> 4 RANGES (cuts at src 65536/106496/139264). Since R19
//      the gathers only need per-dst edges grouped into the 4 phase ranges;
//      within-range order is irrelevant (slab L2-resident). hist2 stride 5
//      (odd -> banks spread, R21 lesson). Scan 25->4 iters.
//  (b) freed LDS -> HALF-BIN blocks (256 dsts): hist2 5.1K + scans 3K +
//      astg 35.3K ~= 43.6KB -> 3 blk/CU, 24 waves; slab read 2x not 4x;
//      grid 784 ~= 768 co-resident (one round). Same XCD swizzle.
// Pre-commit: k_build >=50us -> LDS-atomic chain is the sort floor; pivot
// to gathers (cooperative phase fusion). Everything else = R25.
// MESSAGES STAY FP32 (R7: bf16 fails 0.21).

static constexpr int NN = 200000;
static constexpr int NE = 6400000;
static constexpr int BK = 256;

static constexpr int SUBW  = 512;                    // scat/count bin width (d>>9)
static constexpr int NBA   = (NN + SUBW - 1) / SUBW; // 391 bins
static constexpr int HDS   = 256;                    // dsts per build half
static constexpr int BKB   = 512;                    // build threads
static constexpr int NBB   = ((NBA + 7) / 8) * 8 * 2;// 784 swizzled build blocks
static constexpr int LCAP  = 8832;                   // half staging cap (+7 sigma)
static constexpr int NBL   = 1024;                   // count/scatter blocks
static constexpr int BKC   = 512;                    // threads in count/scatter
static constexpr int SEG   = (NE + NBL - 1) / NBL;   // 6250 edges per block (exact)
static constexpr int T1    = 65536;                  // range cuts (= buckets 8/13/17)
static constexpr int T2    = 106496;
static constexpr int T3    = 139264;

static constexpr int S     = 4;                      // lanes per node in gathers
static constexpr int LOGS  = 2;

// ---------- build pass 1: per-block LDS histogram (no return deps) ----------
__global__ void __launch_bounds__(BKC) k_count(const int* __restrict__ dstI,
                                               int* __restrict__ hist, int e) {
  __shared__ int cnt[NBA];
  for (int t = threadIdx.x; t < NBA; t += BKC) cnt[t] = 0;
  __syncthreads();
  int blk = blockIdx.x;
  int st = blk * SEG, en = st + SEG; if (en > e) en = e;
  int i = st + (int)threadIdx.x;
  for (; i + 3 * BKC < en; i += 4 * BKC) {
    int d0 = __builtin_nontemporal_load(dstI + i);
    int d1 = __builtin_nontemporal_load(dstI + i + BKC);
    int d2 = __builtin_nontemporal_load(dstI + i + 2 * BKC);
    int d3 = __builtin_nontemporal_load(dstI + i + 3 * BKC);
    atomicAdd(&cnt[d0 >> 9], 1);
    atomicAdd(&cnt[d1 >> 9], 1);
    atomicAdd(&cnt[d2 >> 9], 1);
    atomicAdd(&cnt[d3 >> 9], 1);
  }
  for (; i < en; i += BKC) {
    int d = __builtin_nontemporal_load(dstI + i);
    atomicAdd(&cnt[d >> 9], 1);
  }
  __syncthreads();
  for (int t = threadIdx.x; t < NBA; t += BKC) hist[(size_t)t * NBL + blk] = cnt[t];
}

// ---------- build pass 2a: per-bin exclusive scan over 1024 blocks ----------
__global__ void __launch_bounds__(256) k_scanrow(int* __restrict__ hist,
                                                 int* __restrict__ tot) {
  __shared__ int s0[256], s1[256];
  int b = blockIdx.x, t = threadIdx.x;
  int* row = hist + (size_t)b * NBL;
  uint4 vv = ((const uint4*)row)[t];           // row 16B-aligned (NBL%4==0)
  int v0 = (int)vv.x, v1 = (int)vv.y, v2 = (int)vv.z, v3 = (int)vv.w;
  int s = v0 + v1 + v2 + v3;
  s0[t] = s;
  __syncthreads();
  int* a = s0; int* bb = s1;
  for (int o = 1; o < 256; o <<= 1) {
    bb[t] = a[t] + ((t >= o) ? a[t - o] : 0);
    __syncthreads();
    int* tmp = a; a = bb; bb = tmp;
  }
  int ex = a[t] - s;                 // exclusive over quads
  uint4 w;
  w.x = (unsigned)ex;
  w.y = (unsigned)(ex + v0);
  w.z = (unsigned)(ex + v0 + v1);
  w.w = (unsigned)(ex + v0 + v1 + v2);
  ((uint4*)row)[t] = w;
  if (t == 255) tot[b] = a[t];
}

// ---------- build pass 2b: exclusive scan of bin totals -> dense bases ----------
__global__ void k_scanbin(const int* __restrict__ tot, int* __restrict__ sbase) {
  __shared__ int s0[512], s1[512];
  int t = threadIdx.x;
  int v = (t < NBA) ? tot[t] : 0;
  s0[t] = v;
  __syncthreads();
  int* a = s0; int* b = s1;
  for (int o = 1; o < 512; o <<= 1) {
    b[t] = a[t] + ((t >= o) ? a[t - o] : 0);
    __syncthreads();
    int* tmp = a; a = b; b = tmp;
  }
  if (t < NBA) sbase[t] = a[t] - v;
  if (t == NBA - 1) sbase[NBA] = a[t];   // == E
}

// ---------- build pass 3: LDS-staged scatter, per-bin coalesced-run flush ----------
__global__ void __launch_bounds__(BKC) k_scat(const int* __restrict__ srcI,
                                              const int* __restrict__ dstI,
                                              const int* __restrict__ hist,
                                              const int* __restrict__ tot,
                                              const int* __restrict__ sbase,
                                              unsigned* __restrict__ stg, int e) {
  __shared__ int pref[NBA];
  __shared__ int cur[NBA];
  __shared__ unsigned lstg[SEG];
  __shared__ int s0[BKC], s1[BKC];
  int blk = blockIdx.x;
  int t = threadIdx.x;
  int h0 = 0, lc = 0;
  if (t < NBA) {
    h0 = hist[(size_t)t * NBL + blk];
    int h1 = (blk < NBL - 1) ? hist[(size_t)t * NBL + blk + 1] : tot[t];
    lc = h1 - h0;
  }
  s0[t] = lc;
  __syncthreads();
  int* a = s0; int* b = s1;
  for (int o = 1; o < BKC; o <<= 1) {
    b[t] = a[t] + ((t >= o) ? a[t - o] : 0);
    __syncthreads();
    int* tmp = a; a = b; b = tmp;
  }
  if (t < NBA) {
    int ex = a[t] - lc;
    pref[t] = ex;
    cur[t] = ex;
  }
  __syncthreads();
  int st = blk * SEG, en = st + SEG; if (en > e) en = e;
  int i = st + t;
  for (; i + 3 * BKC < en; i += 4 * BKC) {
    int s0v = __builtin_nontemporal_load(srcI + i);
    int d0 = __builtin_nontemporal_load(dstI + i);
    int s1v = __builtin_nontemporal_load(srcI + i + BKC);
    int d1 = __builtin_nontemporal_load(dstI + i + BKC);
    int s2v = __builtin_nontemporal_load(srcI + i + 2 * BKC);
    int d2 = __builtin_nontemporal_load(dstI + i + 2 * BKC);
    int s3v = __builtin_nontemporal_load(srcI + i + 3 * BKC);
    int d3 = __builtin_nontemporal_load(dstI + i + 3 * BKC);
    int p0 = atomicAdd(&cur[d0 >> 9], 1);
    int p1 = atomicAdd(&cur[d1 >> 9], 1);
    int p2 = atomicAdd(&cur[d2 >> 9], 1);
    int p3 = atomicAdd(&cur[d3 >> 9], 1);
    lstg[p0] = ((unsigned)(d0 & (SUBW - 1)) << 18) | (unsigned)s0v;
    lstg[p1] = ((unsigned)(d1 & (SUBW - 1)) << 18) | (unsigned)s1v;
    lstg[p2] = ((unsigned)(d2 & (SUBW - 1)) << 18) | (unsigned)s2v;
    lstg[p3] = ((unsigned)(d3 & (SUBW - 1)) << 18) | (unsigned)s3v;
  }
  for (; i < en; i += BKC) {
    int sv = __builtin_nontemporal_load(srcI + i);
    int d = __builtin_nontemporal_load(dstI + i);
    int p = atomicAdd(&cur[d >> 9], 1);
    lstg[p] = ((unsigned)(d & (SUBW - 1)) << 18) | (unsigned)sv;
  }
  __syncthreads();
  // flush: thread t copies bin t's run; same-thread consecutive stores merge
  if (t < NBA && lc > 0) {
    int lo = pref[t];
    int g = sbase[t] + h0;
    for (int j = 0; j < lc; ++j) stg[g + j] = lstg[lo + j];
  }
}

// ---------- pass 4: half-bin 4-range build, LDS-staged coalesced flush ----------
// XCD-swizzled: halves of one bin share an XCD (8 apart in dispatch) -> bin
// slab L2-hot for half 1. Half h base = bin base + (# half-0 recs) tallied
// during the hist read. hist2 = [dl][range] (stride 5 pads banks).
__global__ void __launch_bounds__(BKB) k_build(const unsigned* __restrict__ stg,
                                               const int* __restrict__ sbase,
                                               int* __restrict__ rowptr,
                                               int* __restrict__ adj,
                                               int* __restrict__ b8,
                                               int* __restrict__ b13,
                                               int* __restrict__ b17) {
  __shared__ unsigned hist2[HDS * 5];      // 5.1 KB: [dl_h][range], slot 4 pad
  __shared__ int htot[HDS];
  __shared__ int s0[HDS], s1[HDS];
  __shared__ unsigned astg[LCAP];          // 35.3 KB staged adj (total ~43.6KB)
  __shared__ int beforeCnt;
  int g = blockIdx.x;
  int x = g & 7, j = g >> 3;
  int h = j & 1;
  int bin = (j >> 1) * 8 + x;              // halves of bin -> same XCD (g%8)
  if (bin >= NBA) return;
  int base = sbase[bin];
  int m = sbase[bin + 1] - base;
  size_t off = (size_t)base;
  if (g == 0 && threadIdx.x == 0) rowptr[NN] = sbase[NBA];   // == E
  for (int t = threadIdx.x; t < HDS * 5; t += BKB) hist2[t] = 0;
  if (threadIdx.x == 0) beforeCnt = 0;
  __syncthreads();
  // read 1: 4-range histogram of this half; count half-0 recs for base_eff
  int myBefore = 0;
  for (int k = threadIdx.x; k < m; k += BKB) {
    unsigned rec = stg[off + k];
    int dl = (int)(rec >> 18);
    if ((dl >> 8) == h) {
      int src = (int)(rec & 0x3FFFFu);
      int r = (src >= T1) + (src >= T2) + (src >= T3);
      atomicAdd(&hist2[(dl & (HDS - 1)) * 5 + r], 1u);
    } else if (h == 1) {
      ++myBefore;
    }
  }
  if (myBefore) atomicAdd(&beforeCnt, myBefore);
  __syncthreads();
  // per-dl exclusive scan over 4 ranges (threads 0..255)
  if (threadIdx.x < HDS) {
    int dl = threadIdx.x;
    unsigned run = 0;
#pragma unroll
    for (int r = 0; r < 4; ++r) {
      unsigned c = hist2[dl * 5 + r];
      hist2[dl * 5 + r] = run;
      run += c;
    }
    htot[dl] = (int)run;
    s0[dl] = (int)run;
  }
  __syncthreads();
  // block inclusive scan over 256 dls (ping-pong, 8 iters)
  int* a = s0; int* bb = s1;
  for (int o2 = 1; o2 < HDS; o2 <<= 1) {
    if (threadIdx.x < HDS) {
      int t = threadIdx.x;
      bb[t] = a[t] + ((t >= o2) ? a[t - o2] : 0);
    }
    __syncthreads();
    int* tmp = a; a = bb; bb = tmp;
  }
  int mytot = a[HDS - 1];
  int base_eff = base + beforeCnt;
  if (threadIdx.x < HDS) {
    int t = threadIdx.x;
    int node = bin * SUBW + h * HDS + t;
    int ex = a[t] - htot[t];
    if (node < NN) {
      rowptr[node] = base_eff + ex;
      b8[node]  = base_eff + ex + (int)hist2[t * 5 + 1];   // exclusive prefixes
      b13[node] = base_eff + ex + (int)hist2[t * 5 + 2];
      b17[node] = base_eff + ex + (int)hist2[t * 5 + 3];
    }
    bb[t] = ex;
  }
  __syncthreads();
  // read 2 (L2-hot): range-ordered scatter into LDS staging (overflow direct)
  for (int k = threadIdx.x; k < m; k += BKB) {
    unsigned rec = stg[off + k];
    int dl = (int)(rec >> 18);
    if ((dl >> 8) != h) continue;
    int src = (int)(rec & 0x3FFFFu);
    int r = (src >= T1) + (src >= T2) + (src >= T3);
    int p = bb[dl & (HDS - 1)] + (int)atomicAdd(&hist2[(dl & (HDS - 1)) * 5 + r], 1u);
    if (p < LCAP) astg[p] = (unsigned)src;
    else adj[base_eff + p] = src;
  }
  __syncthreads();
  // coalesced flush: zero write amplification
  int mm = mytot < LCAP ? mytot : LCAP;
  for (int k = threadIdx.x; k < mm; k += BKB) adj[base_eff + k] = (int)astg[k];
}

// dinv + p1 = dinv*x in one pass (12B rows)
__global__ void k_prep(const float* __restrict__ x, const int* __restrict__ rowptr,
                       float* __restrict__ dinv, float* __restrict__ p1, int n) {
  int i = blockIdx.x * blockDim.x + threadIdx.x;
  if (i >= n) return;
  float di = rsqrtf(1.0f + (float)(rowptr[i + 1] - rowptr[i]));
  dinv[i] = di;
  float3 v;
  v.x = di * x[3 * (size_t)i];
  v.y = di * x[3 * (size_t)i + 1];
  v.z = di * x[3 * (size_t)i + 2];
  *(float3*)(p1 + 3 * (size_t)i) = v;
}

// ---------- packed-row load/accumulate/store (RW floats per row) ----------
template <int RW> struct RowT;
template <> struct RowT<3> {
  using T = float3;   // 12B rows
  static __device__ inline T ld(const float* __restrict__ p) { return *(const float3*)p; }
  static __device__ inline void add(float* __restrict__ a, const T& v) {
    a[0] += v.x; a[1] += v.y; a[2] += v.z;
  }
  static __device__ inline void st(float* __restrict__ p, const float* __restrict__ a) {
    *(float3*)p = make_float3(a[0], a[1], a[2]);
  }
};
template <> struct RowT<6> {
  struct T { float2 a, b, c; };       // 24B rows, 8B-aligned
  static __device__ inline T ld(const float* __restrict__ p) {
    T t; t.a = *(const float2*)p; t.b = *(const float2*)(p + 2); t.c = *(const float2*)(p + 4);
    return t;
  }
  static __device__ inline void add(float* __restrict__ a, const T& v) {
    a[0] += v.a.x; a[1] += v.a.y; a[2] += v.b.x; a[3] += v.b.y; a[4] += v.c.x; a[5] += v.c.y;
  }
  static __device__ inline void st(float* __restrict__ p, const float* __restrict__ a) {
    *(float2*)(p)     = make_float2(a[0], a[1]);
    *(float2*)(p + 2) = make_float2(a[2], a[3]);
    *(float2*)(p + 4) = make_float2(a[4], a[5]);
  }
};
template <> struct RowT<12> {
  struct T { float4 a, b, c; };       // 48B rows, 16B-aligned bases
  static __device__ inline T ld(const float* __restrict__ p) {
    T t; t.a = *(const float4*)p; t.b = *(const float4*)(p + 4); t.c = *(const float4*)(p + 8);
    return t;
  }
  static __device__ inline void add(float* __restrict__ a, const T& v) {
    a[0] += v.a.x; a[1] += v.a.y; a[2] += v.a.z; a[3] += v.a.w;
    a[4] += v.b.x; a[5] += v.b.y; a[6] += v.b.z; a[7] += v.b.w;
    a[8] += v.c.x; a[9] += v.c.y; a[10] += v.c.z; a[11] += v.c.w;
  }
  static __device__ inline void st(float* __restrict__ p, const float* __restrict__ a) {
    *(float4*)(p)     = make_float4(a[0], a[1], a[2], a[3]);
    *(float4*)(p + 4) = make_float4(a[4], a[5], a[6], a[7]);
    *(float4*)(p + 8) = make_float4(a[8], a[9], a[10], a[11]);
  }
};

// ---------- slot-strided gather over [st,en), unroll UN, adj prefetch 1 ahead ----------
template <int RW, int UN>
__device__ inline void gather_p(const int* __restrict__ adj, int st, int en,
                                const float* __restrict__ pin, float* __restrict__ acc,
                                int slot) {
  using RT = RowT<RW>;
  using T = typename RT::T;
  int k = st + slot;
  if (k + (UN - 1) * S < en) {
    int a[UN];
#pragma unroll
    for (int u = 0; u < UN; ++u) a[u] = adj[k + u * S];
    for (;;) {
      int kn = k + UN * S;
      bool more = (kn + (UN - 1) * S < en);
      int b[UN];
#pragma unroll
      for (int u = 0; u < UN; ++u) b[u] = 0;
      if (more) {
#pragma unroll
        for (int u = 0; u < UN; ++u) b[u] = adj[kn + u * S];
      }
      T v[UN];
#pragma unroll
      for (int u = 0; u < UN; ++u) v[u] = RT::ld(pin + (size_t)a[u] * RW);
#pragma unroll
      for (int u = 0; u < UN; ++u) RT::add(acc, v[u]);
      k = kn;
      if (!more) break;
#pragma unroll
      for (int u = 0; u < UN; ++u) a[u] = b[u];
    }
  }
  for (; k < en; k += S) {
    T v = RT::ld(pin + (size_t)adj[k] * RW);
    RT::add(acc, v);
  }
}

// 4-lane butterfly: all lanes end with the full sum
template <int FIN>
__device__ inline void group_reduce(float* __restrict__ acc) {
#pragma unroll
  for (int j = 0; j < FIN; ++j) {
    acc[j] += __shfl_xor(acc[j], 1);
    acc[j] += __shfl_xor(acc[j], 2);
  }
}

// ---------- single-phase fused gather (layer 1 only; slab fits L2) ----------
template <int RW, int FOUT, int MODE>
__global__ void __launch_bounds__(BK, 8) k_gather_fused(
    const int* __restrict__ adj, const int* __restrict__ rowptr,
    const float* __restrict__ pin, const float* __restrict__ W,
    const float* __restrict__ bias, const float* __restrict__ dinv,
    float* __restrict__ pout, int n) {
  __shared__ float sW[RW * FOUT];
  __shared__ float sb[FOUT];
  for (int t = threadIdx.x; t < RW * FOUT; t += BK) sW[t] = W[t];
  if (threadIdx.x < FOUT) sb[threadIdx.x] = bias[threadIdx.x];
  __syncthreads();
  int g = blockIdx.x * blockDim.x + threadIdx.x;
  int i = g >> LOGS;
  int slot = g & (S - 1);
  if (i >= n) return;
  float acc[RW] = {};
  if (slot == 0) {                                  // self-loop on slot 0
    typename RowT<RW>::T v = RowT<RW>::ld(pin + (size_t)i * RW);
    RowT<RW>::add(acc, v);
  }
  gather_p<RW, 4>(adj, rowptr[i], rowptr[i + 1], pin, acc, slot);
  group_reduce<RW>(acc);
  float di = dinv[i];
  float h[FOUT];
  float ss = 0.f;
#pragma unroll
  for (int j = 0; j < FOUT; ++j) {
    float s = 0.f;
#pragma unroll
    for (int kk = 0; kk < RW; ++kk) s = fmaf(acc[kk], sW[kk * FOUT + j], s);
    float t = fmaf(di, s, sb[j]);
    h[j] = t;
    ss += t * t;
  }
  float o[FOUT];
  if (MODE == 0) {
#pragma unroll
    for (int j = 0; j < FOUT; ++j) o[j] = di * tanhf(h[j]);
  } else {
    float inv = 1.f / fmaxf(sqrtf(ss), 1e-12f);
#pragma unroll
    for (int j = 0; j < FOUT; ++j) o[j] = di * tanhf(h[j] * inv);
  }
  if (slot == 0) {
    float* po = pout + (size_t)i * FOUT;
    if (MODE == 0) {                                 // 24B rows: 3x float2
      *(float2*)(po)     = make_float2(o[0], o[1]);
      *(float2*)(po + 2) = make_float2(o[2], o[3]);
      *(float2*)(po + 4) = make_float2(o[4], o[5]);
    } else {                                         // 48B rows: 3x float4
      *(float4*)(po)     = make_float4(o[0], o[1], o[2], o[3]);
      *(float4*)(po + 4) = make_float4(o[4], o[5], o[6], o[7]);
      *(float4*)(po + 8) = make_float4(o[8], o[9], o[10], o[11]);
    }
  }
}

// ---------- phased gather: one src-range slab per kernel launch ----------
// FIRST: acc = self-loop; else acc = reload packed partial (slot 0 holds it).
template <int RW, bool FIRST>
__global__ void __launch_bounds__(BK, 8) k_gphase(
    const int* __restrict__ adj, const int* __restrict__ stA,
    const int* __restrict__ enB, const float* __restrict__ pin,
    float* __restrict__ accb, int n) {
  int g = blockIdx.x * blockDim.x + threadIdx.x;
  int i = g >> LOGS;
  int slot = g & (S - 1);
  if (i >= n) return;
  float acc[RW] = {};
  if (slot == 0) {
    if (FIRST) {
      typename RowT<RW>::T v = RowT<RW>::ld(pin + (size_t)i * RW);  // self-loop
      RowT<RW>::add(acc, v);
    } else {
      typename RowT<RW>::T v = RowT<RW>::ld(accb + (size_t)i * RW); // partial
      RowT<RW>::add(acc, v);
    }
  }
  gather_p<RW, 4>(adj, stA[i], enB[i], pin, acc, slot);
  group_reduce<RW>(acc);
  if (slot == 0) RowT<RW>::st(accb + (size_t)i * RW, acc);
}

// ---------- final phase: last slab + epilogue ----------
// MODE 1: l2norm+tanh -> pout (48B rows for FOUT=12)
// MODE 2: l2norm -> Wc -> l2norm -> out (13 floats)
template <int RW, int FOUT, int MODE>
__global__ void __launch_bounds__(BK, 6) k_gphase_last(
    const int* __restrict__ adj, const int* __restrict__ stA,
    const int* __restrict__ rowptr, const float* __restrict__ pin,
    const float* __restrict__ W, const float* __restrict__ bias,
    const float* __restrict__ Wc, const float* __restrict__ bc,
    const float* __restrict__ dinv, const float* __restrict__ accb,
    float* __restrict__ out, int n) {
  constexpr int FC = 13;
  __shared__ float sW[RW * FOUT];
  __shared__ float sb[FOUT];
  __shared__ float sWc[MODE == 2 ? FOUT * FC : 1];
  __shared__ float sbc[MODE == 2 ? FC : 1];
  for (int t = threadIdx.x; t < RW * FOUT; t += BK) sW[t] = W[t];
  if (threadIdx.x < FOUT) sb[threadIdx.x] = bias[threadIdx.x];
  if (MODE == 2) {
    for (int t = threadIdx.x; t < FOUT * FC; t += BK) sWc[t] = Wc[t];
    if (threadIdx.x < FC) sbc[threadIdx.x] = bc[threadIdx.x];
  }
  __syncthreads();
  int g = blockIdx.x * blockDim.x + threadIdx.x;
  int i = g >> LOGS;
  int slot = g & (S - 1);
  if (i >= n) return;
  float acc[RW] = {};
  if (slot == 0) {
    typename RowT<RW>::T v = RowT<RW>::ld(accb + (size_t)i * RW);   // partial
    RowT<RW>::add(acc, v);
  }
  gather_p<RW, 4>(adj, stA[i], rowptr[i + 1], pin, acc, slot);
  group_reduce<RW>(acc);
  float di = dinv[i];
  float h[FOUT];
  float ss = 0.f;
#pragma unroll
  for (int j = 0; j < FOUT; ++j) {
    float s = 0.f;
#pragma unroll
    for (int kk = 0; kk < RW; ++kk) s = fmaf(acc[kk], sW[kk * FOUT + j], s);
    float t = fmaf(di, s, sb[j]);
    h[j] = t;
    ss += t * t;
  }
  float inv = 1.f / fmaxf(sqrtf(ss), 1e-12f);
  if (MODE == 1) {
    float o[FOUT];
#pragma unroll
    for (int j = 0; j < FOUT; ++j) o[j] = di * tanhf(h[j] * inv);
    if (slot == 0) {
      float* po = out + (size_t)i * FOUT;                  // 48B rows (FOUT=12)
      *(float4*)(po)     = make_float4(o[0], o[1], o[2], o[3]);
      *(float4*)(po + 4) = make_float4(o[4], o[5], o[6], o[7]);
      *(float4*)(po + 8) = make_float4(o[8], o[9], o[10], o[11]);
    }
  } else {
    float v[FC];
    float ss2 = 0.f;
#pragma unroll
    for (int j = 0; j < FC; ++j) {
      float s = sbc[j];
#pragma unroll
      for (int kk = 0; kk < FOUT; ++kk) s = fmaf(h[kk] * inv, sWc[kk * FC + j], s);
      v[j] = s;
      ss2 += s * s;
    }
    float inv2 = 1.f / fmaxf(sqrtf(ss2), 1e-12f);
    if (slot == 0) {
#pragma unroll
      for (int j = 0; j < FC; ++j) out[(size_t)i * FC + j] = v[j] * inv2;
    }
  }
}

extern "C" void kernel_launch(void* const* d_in, const int* in_sizes, int n_in,
                              void* d_out, int out_size, void* d_ws, size_t ws_size,
                              hipStream_t stream) {
  const float* x  = (const float*)d_in[0];
  const int*   ei = (const int*)d_in[1];
  const float* W1 = (const float*)d_in[2];
  const float* b1 = (const float*)d_in[3];
  const float* W2 = (const float*)d_in[4];
  const float* b2 = (const float*)d_in[5];
  const float* W3 = (const float*)d_in[6];
  const float* b3 = (const float*)d_in[7];
  const float* Wc = (const float*)d_in[8];
  const float* bc = (const float*)d_in[9];
  float* out = (float*)d_out;

  const int n = NN;
  const int e = NE;
  const int* srcI = ei;       // row 0
  const int* dstI = ei + e;   // row 1

  // Workspace (words):
  //   dinv[N] | rowptr[N+8] | sbase[512] | tot[512] | hist[NBA*NBL] | adj[E]
  //   | b8[N] | b13[N] | b17[N] | pad->64B | R
  // R hosts dense stg[E]=6.4M words during build, then
  //   p1[3N] | p2[6N] | p3[12N] | accb[12N] (=6.6M words) during gathers.
  // hist = 391*1024 = 400384 words (1.6MB). Total ~= 58 MB (<=76 MB proven).
  float* ws = (float*)d_ws;
  float* dinv  = ws;
  int* rowptr  = (int*)(ws + n);            // N+8 (uses N+1, padded)
  int* sbase   = rowptr + n + 8;            // NBA+1 used
  int* tot     = sbase + 512;
  int* hist    = tot + 512;                 // NBA * NBL (16B-aligned)
  int* adj     = hist + NBA * NBL;
  int* b8      = adj + e;
  int* b13     = b8 + n;
  int* b17     = b13 + n;
  size_t roff = (size_t)n + (n + 8) + 512 + 512 + (size_t)NBA * NBL + e + 3 * (size_t)n;
  roff = (roff + 15) & ~(size_t)15;         // round to 16 words = 64B
  float* R     = ws + roff;
  unsigned* stg = (unsigned*)R;             // dense E words during build
  float* p1   = R;                          // 3N
  float* p2   = R + (size_t)3 * n;          // 6N
  float* p3   = R + (size_t)9 * n;          // 12N
  float* accb = R + (size_t)21 * n;         // 12N packed partials (16B-aligned)

  const int gn  = (n + BK - 1) / BK;
  const int gnS = (n * S + BK - 1) / BK;    // 3125 blocks

  // --- CSR build: count -> scan -> LDS-staged scatter -> half-bin 4-range build ---
  k_count<<<NBL, BKC, 0, stream>>>(dstI, hist, e);
  k_scanrow<<<NBA, 256, 0, stream>>>(hist, tot);
  k_scanbin<<<1, 512, 0, stream>>>(tot, sbase);
  k_scat<<<NBL, BKC, 0, stream>>>(srcI, dstI, hist, tot, sbase, stg, e);
  k_build<<<NBB, BKB, 0, stream>>>(stg, sbase, rowptr, adj, b8, b13, b17);

  // --- dinv + p1 = dinv * x (12B rows) ---
  k_prep<<<gn, BK, 0, stream>>>(x, rowptr, dinv, p1, n);

  // --- Layer 1 (p1 = 2.4 MB, fits per-XCD L2): single fused phase ---
  k_gather_fused<3, 6, 0><<<gnS, BK, 0, stream>>>(adj, rowptr, p1, W1, b1, dinv, p2, n);

  // --- Layer 2 (p2 = 4.8 MB): 2 phases, cut at b13 ---
  k_gphase<6, true><<<gnS, BK, 0, stream>>>(adj, rowptr, b13, p2, accb, n);
  k_gphase_last<6, 12, 1><<<gnS, BK, 0, stream>>>(adj, b13, rowptr, p2, W2, b2,
                                                  Wc, bc, dinv, accb, p3, n);

  // --- Layer 3 + classifier (p3 = 9.6 MB): 3 phases, cuts at b8/b17 ---
  k_gphase<12, true><<<gnS, BK, 0, stream>>>(adj, rowptr, b8, p3, accb, n);
  k_gphase<12, false><<<gnS, BK, 0, stream>>>(adj, b8, b17, p3, accb, n);
  k_gphase_last<12, 24, 2><<<gnS, BK, 0, stream>>>(adj, b17, rowptr, p3, W3, b3,
                                                   Wc, bc, dinv, accb, out, n);
}